// Round 14
// baseline (684.009 us; speedup 1.0000x reference)
//
#include <hip/hip_runtime.h>
#include <math.h>

#define NN   131072   // total inner nodes
#define GG   2048     // graphs
#define NPG  64       // nodes per graph
#define EE   1048576  // inner edges
#define EFN  32768    // outer edges
#define DD   128      // feature dim
#define KK   8        // sortpool k

typedef unsigned short bfu;  // raw bf16 bits
typedef short bf16x8 __attribute__((ext_vector_type(8)));
typedef float f32x4 __attribute__((ext_vector_type(4)));

static __device__ __forceinline__ bfu f2b(float f) {  // RNE f32 -> bf16
  unsigned u = __float_as_uint(f);
  u += 0x7FFFu + ((u >> 16) & 1u);
  return (bfu)(u >> 16);
}
static __device__ __forceinline__ float b2f(bfu b) {
  return __uint_as_float(((unsigned)b) << 16);
}

// ---------------- utility ----------------
__global__ void fill_f32_kernel(float* __restrict__ p, float v, int nElems) {
  int i = blockIdx.x * 256 + threadIdx.x;
  if (i < nElems) p[i] = v;
}

__global__ void zero_int_kernel(int* __restrict__ p, int nElems) {
  int i = blockIdx.x * 256 + threadIdx.x;
  if (i < nElems) p[i] = 0;
}

__global__ void init_softmax_kernel(float* __restrict__ mx, float* __restrict__ sm, int nElems) {
  int i = blockIdx.x * 256 + threadIdx.x;
  if (i < nElems) { mx[i] = -INFINITY; sm[i] = 0.f; }
}

// x[i] = relu(token_emb[h[node]][d])   (fallback path only)
__global__ void embed_relu_kernel(const float* __restrict__ temb,
                                  const int* __restrict__ h,
                                  float* __restrict__ x, int total) {
  int i = blockIdx.x * 256 + threadIdx.x;
  if (i >= total) return;
  int node = i >> 7, d = i & 127;
  x[i] = fmaxf(temb[h[node] * DD + d], 0.f);
}

// ---------------- small / generic GEMM (outer graph, fallback) ----------------
template <int KD, int ROWS>
__global__ __launch_bounds__(128) void gemm_kernel(
    const float* __restrict__ A, const float* __restrict__ W,
    const float* __restrict__ bias, float* __restrict__ out,
    int relu_flag) {
  __shared__ float As[ROWS * KD];
  const int row0 = blockIdx.x * ROWS;
  const int tid = threadIdx.x;
  for (int i = tid; i < ROWS * KD; i += 128) As[i] = A[(size_t)row0 * KD + i];
  __syncthreads();
  float acc[ROWS];
#pragma unroll
  for (int r = 0; r < ROWS; r++) acc[r] = 0.f;
  for (int k = 0; k < KD; k++) {
    float w = W[k * 128 + tid];
#pragma unroll
    for (int r = 0; r < ROWS; r++) acc[r] += As[r * KD + k] * w;
  }
  float b = bias ? bias[tid] : 0.f;
#pragma unroll
  for (int r = 0; r < ROWS; r++) {
    float v = acc[r] + b;
    if (relu_flag) v = fmaxf(v, 0.f);
    out[(size_t)(row0 + r) * 128 + tid] = v;
  }
}

// ---------------- outer-GAT GEMM: f3[G,128] = xp[G,1024] @ W3[1024,128] ----------------
__global__ __launch_bounds__(256) void gemm1024_kernel(
    const float* __restrict__ A, const float* __restrict__ W,
    float* __restrict__ out) {
  __shared__ float As[8 * 1024];
  __shared__ float red[8][256];
  const int t = threadIdx.x;
  const int row0 = blockIdx.x * 8;
  for (int idx = t; idx < 8 * 256; idx += 256) {
    int r = idx >> 8, c4 = (idx & 255) << 2;
    *(float4*)&As[r * 1024 + c4] = *(const float4*)(A + (size_t)(row0 + r) * 1024 + c4);
  }
  __syncthreads();
  const int col = t & 127, kh = t >> 7;
  const int k0 = kh * 512;
  float acc[8];
#pragma unroll
  for (int r = 0; r < 8; r++) acc[r] = 0.f;
  for (int k = k0; k < k0 + 512; k += 4) {
    float w0 = W[(size_t)(k + 0) * 128 + col];
    float w1 = W[(size_t)(k + 1) * 128 + col];
    float w2 = W[(size_t)(k + 2) * 128 + col];
    float w3 = W[(size_t)(k + 3) * 128 + col];
#pragma unroll
    for (int r = 0; r < 8; r++) {
      float4 a = *(const float4*)&As[r * 1024 + k];
      acc[r] += a.x * w0 + a.y * w1 + a.z * w2 + a.w * w3;
    }
  }
#pragma unroll
  for (int r = 0; r < 8; r++) red[r][t] = acc[r];
  __syncthreads();
  for (int idx = t; idx < 1024; idx += 256) {
    int r = idx >> 7, c = idx & 127;
    out[(size_t)(row0 + r) * 128 + c] = red[r][c] + red[r][128 + c];
  }
}

// ---------------- MFMA split-precision GEMM: out = act(A)[M,128] @ W[128,128] ----------------
// 3-term bf16 split (A_hi*W_hi + A_hi*W_lo + A_lo*W_hi) ~ fp32 accuracy.
// W staged transposed+split into 2 XOR-swizzled LDS arrays (32KB each).
// 256 thr = 4 waves x 16 rows. Fragment layouts per verified guide:
//   A: m=lane&15, k=quad*8+j ; C/D: col=lane&15, row=quad*4+reg.
// EPI 1: store bf16 F + fp32 el/er.  EPI 2: bias+relu fp32 (in-place ok) + rowmax.
template <int SRC_MODE, int EPI>
__global__ __launch_bounds__(256) void mfma_gemm(
    const float* A, const float* __restrict__ temb,
    const int* __restrict__ hidx, const float* __restrict__ W,
    const float* __restrict__ bias, void* out,
    const float* __restrict__ al, const float* __restrict__ ar,
    float* __restrict__ el, float* __restrict__ er,
    float* __restrict__ keyb) {
  __shared__ bfu WtHi[128 * 128];
  __shared__ bfu WtLo[128 * 128];
  const int t = threadIdx.x;
  // stage W[k][n] -> Wt[n][k] split hi/lo, chunk-swizzled: chunk c=k>>3 stored at c^(n&15)
  for (int idx = t; idx < 128 * 32; idx += 256) {
    int k = idx >> 5, n4 = (idx & 31) << 2;
    float4 w = *(const float4*)(W + (size_t)k * 128 + n4);
    float wv[4] = {w.x, w.y, w.z, w.w};
    int c = k >> 3, k7 = k & 7;
#pragma unroll
    for (int i = 0; i < 4; i++) {
      int n = n4 + i;
      bfu hi = f2b(wv[i]);
      bfu lo = f2b(wv[i] - b2f(hi));
      int pos = n * 128 + ((c ^ (n & 15)) << 3) + k7;
      WtHi[pos] = hi;
      WtLo[pos] = lo;
    }
  }
  __syncthreads();
  const int lane = t & 63, wv_ = t >> 6;
  const int m16 = lane & 15, quad = lane >> 4;
  const int rowbase = blockIdx.x * 64 + wv_ * 16;
  const int grow = rowbase + m16;
  const float* arow = (SRC_MODE == 1) ? (temb + (size_t)hidx[grow] * 128)
                                      : (A + (size_t)grow * 128);
  f32x4 acc[8];
#pragma unroll
  for (int i = 0; i < 8; i++) acc[i] = (f32x4){0.f, 0.f, 0.f, 0.f};
  for (int kk = 0; kk < 128; kk += 32) {
    int k0 = kk + quad * 8;
    float av[8];
    *(float4*)&av[0] = *(const float4*)(arow + k0);
    *(float4*)&av[4] = *(const float4*)(arow + k0 + 4);
    if (SRC_MODE == 1) {
#pragma unroll
      for (int i = 0; i < 8; i++) av[i] = fmaxf(av[i], 0.f);
    }
    bf16x8 ahi, alo;
#pragma unroll
    for (int i = 0; i < 8; i++) {
      bfu hi = f2b(av[i]);
      bfu lo = f2b(av[i] - b2f(hi));
      ahi[i] = (short)hi;
      alo[i] = (short)lo;
    }
    int c = k0 >> 3;
#pragma unroll
    for (int tt = 0; tt < 8; tt++) {
      int n = tt * 16 + m16;
      int pos = n * 128 + ((c ^ (n & 15)) << 3);
      bf16x8 bhi = *(const bf16x8*)&WtHi[pos];
      bf16x8 blo = *(const bf16x8*)&WtLo[pos];
      acc[tt] = __builtin_amdgcn_mfma_f32_16x16x32_bf16(ahi, bhi, acc[tt], 0, 0, 0);
      acc[tt] = __builtin_amdgcn_mfma_f32_16x16x32_bf16(ahi, blo, acc[tt], 0, 0, 0);
      acc[tt] = __builtin_amdgcn_mfma_f32_16x16x32_bf16(alo, bhi, acc[tt], 0, 0, 0);
    }
  }
  // epilogue: lane holds D[row=rowbase+quad*4+r][col=tt*16+m16]
  if (EPI == 1) {
    float pl[4] = {0.f, 0.f, 0.f, 0.f}, pr[4] = {0.f, 0.f, 0.f, 0.f};
#pragma unroll
    for (int tt = 0; tt < 8; tt++) {
      int col = tt * 16 + m16;
      float alv = al[col], arv = ar[col];
#pragma unroll
      for (int r = 0; r < 4; r++) {
        float v = acc[tt][r];
        ((bfu*)out)[(size_t)(rowbase + quad * 4 + r) * 128 + col] = f2b(v);
        pl[r] += v * alv;
        pr[r] += v * arv;
      }
    }
#pragma unroll
    for (int r = 0; r < 4; r++) {
      float a0 = pl[r], a1 = pr[r];
#pragma unroll
      for (int off = 1; off < 16; off <<= 1) {
        a0 += __shfl_xor(a0, off);
        a1 += __shfl_xor(a1, off);
      }
      if (m16 == 0) {
        el[rowbase + quad * 4 + r] = a0;
        er[rowbase + quad * 4 + r] = a1;
      }
    }
  } else {  // EPI == 2
    float pm[4] = {-INFINITY, -INFINITY, -INFINITY, -INFINITY};
#pragma unroll
    for (int tt = 0; tt < 8; tt++) {
      int col = tt * 16 + m16;
      float bv = bias[col];
#pragma unroll
      for (int r = 0; r < 4; r++) {
        float v = fmaxf(acc[tt][r] + bv, 0.f);
        ((float*)out)[(size_t)(rowbase + quad * 4 + r) * 128 + col] = v;
        pm[r] = fmaxf(pm[r], v);
      }
    }
#pragma unroll
    for (int r = 0; r < 4; r++) {
      float a0 = pm[r];
#pragma unroll
      for (int off = 1; off < 16; off <<= 1) a0 = fmaxf(a0, __shfl_xor(a0, off));
      if (m16 == 0) keyb[rowbase + quad * 4 + r] = a0;
    }
  }
}

// ---------------- attention logits (outer graph, fallback) ----------------
__global__ __launch_bounds__(64) void attn_logits_kernel(
    const float* __restrict__ f, const float* __restrict__ al,
    const float* __restrict__ ar, float* __restrict__ el,
    float* __restrict__ er) {
  int node = blockIdx.x, lane = threadIdx.x;
  float v1 = f[(size_t)node * 128 + lane];
  float v2 = f[(size_t)node * 128 + 64 + lane];
  float sl = v1 * al[lane] + v2 * al[64 + lane];
  float sr = v1 * ar[lane] + v2 * ar[64 + lane];
#pragma unroll
  for (int off = 32; off; off >>= 1) {
    sl += __shfl_down(sl, off);
    sr += __shfl_down(sr, off);
  }
  if (lane == 0) { el[node] = sl; er[node] = sr; }
}

// ---------------- CSR build ----------------
__global__ void hist_kernel(const int* __restrict__ dst, int* __restrict__ cnt, int nE) {
  int e = blockIdx.x * 256 + threadIdx.x;
  if (e < nE) atomicAdd(&cnt[dst[e]], 1);
}

__global__ __launch_bounds__(256) void scan_block_kernel(
    const int* __restrict__ cnt, int* __restrict__ excl, int* __restrict__ part) {
  __shared__ int s[256];
  int blk = blockIdx.x, tid = threadIdx.x;
  int base = blk * 1024 + tid * 4;
  int a0 = cnt[base], a1 = cnt[base + 1], a2 = cnt[base + 2], a3 = cnt[base + 3];
  int tsum = a0 + a1 + a2 + a3;
  s[tid] = tsum; __syncthreads();
  for (int off = 1; off < 256; off <<= 1) {
    int v = (tid >= off) ? s[tid - off] : 0;
    __syncthreads();
    s[tid] += v;
    __syncthreads();
  }
  int texcl = s[tid] - tsum;
  excl[base]     = texcl;
  excl[base + 1] = texcl + a0;
  excl[base + 2] = texcl + a0 + a1;
  excl[base + 3] = texcl + a0 + a1 + a2;
  if (tid == 255) part[blk] = s[255];
}

__global__ __launch_bounds__(128) void scan_part_kernel(int* __restrict__ part) {
  __shared__ int s[128];
  int tid = threadIdx.x;
  int orig = part[tid];
  s[tid] = orig; __syncthreads();
  for (int off = 1; off < 128; off <<= 1) {
    int v = (tid >= off) ? s[tid - off] : 0;
    __syncthreads();
    s[tid] += v;
    __syncthreads();
  }
  part[tid] = s[tid] - orig;
}

__global__ void scan_add_kernel(int* __restrict__ row_ptr, const int* __restrict__ part,
                                int n, int total) {
  int i = blockIdx.x * 256 + threadIdx.x;
  if (i < n) row_ptr[i] += part[i >> 10];
  if (i == 0) row_ptr[n] = total;
}

__global__ void scatter_kernel(const int* __restrict__ dst, const int* __restrict__ src,
                               const int* __restrict__ row_ptr,
                               int* __restrict__ cursor, int* __restrict__ adj_src, int nE) {
  int e = blockIdx.x * 256 + threadIdx.x;
  if (e >= nE) return;
  int d = dst[e];
  int pos = row_ptr[d] + atomicAdd(&cursor[d], 1);
  adj_src[pos] = src[e];
}

// ---------------- fused CSR GAT aggregation: one 64-lane wave per dst ----------------
__global__ __launch_bounds__(256) void gat_aggregate_csr_kernel(
    const bfu* __restrict__ F, const float* __restrict__ el,
    const float* __restrict__ er, const int* __restrict__ row_ptr,
    const int* __restrict__ adj_src,
    const float* __restrict__ bias, float* __restrict__ outX) {
  const int lane = threadIdx.x & 63;
  const int d = blockIdx.x * 4 + (threadIdx.x >> 6);
  const int c0 = lane * 2;
  int beg = row_ptr[d];
  int n = row_ptr[d + 1] - beg;
  float2 bv = *(const float2*)&bias[c0];
  if (n == 0) {
    float2 o; o.x = fmaxf(bv.x, 0.f); o.y = fmaxf(bv.y, 0.f);
    *(float2*)&outX[(size_t)d * 128 + c0] = o;
    return;
  }
  float er_d = er[d];
  float2 acc = make_float2(0.f, 0.f);
  if (n <= 64) {
    int sv = 0; float sc = -INFINITY;
    if (lane < n) {
      sv = adj_src[beg + lane];
      float v = el[sv] + er_d;
      sc = v > 0.f ? v : 0.2f * v;
    }
    float m = sc;
#pragma unroll
    for (int off = 32; off; off >>= 1) m = fmaxf(m, __shfl_xor(m, off));
    float ex = (lane < n) ? expf(sc - m) : 0.f;
    float s = ex;
#pragma unroll
    for (int off = 32; off; off >>= 1) s += __shfl_xor(s, off);
    float wt = ex / s;
    for (int j = 0; j < n; j += 4) {
      int   s0 = __shfl(sv, j);
      float w0 = __shfl(wt, j);
      int   j1 = (j + 1 < n) ? j + 1 : j;
      int   s1 = __shfl(sv, j1); float w1 = (j + 1 < n) ? __shfl(wt, j1) : 0.f;
      int   j2 = (j + 2 < n) ? j + 2 : j;
      int   s2 = __shfl(sv, j2); float w2 = (j + 2 < n) ? __shfl(wt, j2) : 0.f;
      int   j3 = (j + 3 < n) ? j + 3 : j;
      int   s3 = __shfl(sv, j3); float w3 = (j + 3 < n) ? __shfl(wt, j3) : 0.f;
      ushort2 f0 = *(const ushort2*)&F[(size_t)s0 * 128 + c0];
      ushort2 f1 = *(const ushort2*)&F[(size_t)s1 * 128 + c0];
      ushort2 f2 = *(const ushort2*)&F[(size_t)s2 * 128 + c0];
      ushort2 f3 = *(const ushort2*)&F[(size_t)s3 * 128 + c0];
      acc.x += w0 * b2f(f0.x) + w1 * b2f(f1.x) + w2 * b2f(f2.x) + w3 * b2f(f3.x);
      acc.y += w0 * b2f(f0.y) + w1 * b2f(f1.y) + w2 * b2f(f2.y) + w3 * b2f(f3.y);
    }
  } else {
    float lm = -INFINITY;
    for (int t = lane; t < n; t += 64) {
      int sv = adj_src[beg + t];
      float v = el[sv] + er_d;
      v = v > 0.f ? v : 0.2f * v;
      lm = fmaxf(lm, v);
    }
#pragma unroll
    for (int off = 32; off; off >>= 1) lm = fmaxf(lm, __shfl_xor(lm, off));
    float ls = 0.f;
    for (int t = lane; t < n; t += 64) {
      int sv = adj_src[beg + t];
      float v = el[sv] + er_d;
      v = v > 0.f ? v : 0.2f * v;
      ls += expf(v - lm);
    }
#pragma unroll
    for (int off = 32; off; off >>= 1) ls += __shfl_xor(ls, off);
    for (int base = 0; base < n; base += 64) {
      int t = base + lane;
      int sv = 0; float wt = 0.f;
      if (t < n) {
        sv = adj_src[beg + t];
        float v = el[sv] + er_d;
        v = v > 0.f ? v : 0.2f * v;
        wt = expf(v - lm) / ls;
      }
      int cnt = min(64, n - base);
      for (int j = 0; j < cnt; ++j) {
        int s0 = __shfl(sv, j);
        float w0 = __shfl(wt, j);
        ushort2 f0 = *(const ushort2*)&F[(size_t)s0 * 128 + c0];
        acc.x += w0 * b2f(f0.x);
        acc.y += w0 * b2f(f0.y);
      }
    }
  }
  float2 o;
  o.x = fmaxf(acc.x + bv.x, 0.f);
  o.y = fmaxf(acc.y + bv.y, 0.f);
  *(float2*)&outX[(size_t)d * 128 + c0] = o;
}

// ---------------- atomic-path edge kernels (outer graph + fallback) ----------------
static __device__ __forceinline__ void atomicMaxF(float* addr, float v) {
  int iv = __float_as_int(v);
  if (iv >= 0) atomicMax((int*)addr, iv);
  else atomicMin((unsigned int*)addr, (unsigned int)iv);
}

static __device__ __forceinline__ float edge_score(const float* el, const float* er,
                                                   int sv, int dv) {
  float v = el[sv] + er[dv];
  return v > 0.f ? v : 0.2f * v;
}

__global__ void edge_max_kernel(const float* __restrict__ el,
                                const float* __restrict__ er,
                                const int* __restrict__ src,
                                const int* __restrict__ dst,
                                float* __restrict__ m, int nE) {
  int e = blockIdx.x * 256 + threadIdx.x;
  if (e >= nE) return;
  atomicMaxF(&m[dst[e]], edge_score(el, er, src[e], dst[e]));
}

__global__ void edge_expsum_kernel(const float* __restrict__ el,
                                   const float* __restrict__ er,
                                   const float* __restrict__ m,
                                   const int* __restrict__ src,
                                   const int* __restrict__ dst,
                                   float* __restrict__ s, int nE) {
  int e = blockIdx.x * 256 + threadIdx.x;
  if (e >= nE) return;
  int d = dst[e];
  atomicAdd(&s[d], expf(edge_score(el, er, src[e], d) - m[d]));
}

__global__ __launch_bounds__(128) void edge_aggregate_kernel(
    const float* __restrict__ f, const float* __restrict__ el,
    const float* __restrict__ er, const float* __restrict__ m,
    const float* __restrict__ s, const int* __restrict__ src,
    const int* __restrict__ dst, float* __restrict__ out, int nE) {
  int e = blockIdx.x;
  int d = threadIdx.x;
  int sv = src[e], dv = dst[e];
  float alpha = expf(edge_score(el, er, sv, dv) - m[dv]) / s[dv];
  atomicAdd(&out[(size_t)dv * 128 + d], alpha * f[(size_t)sv * 128 + d]);
}

__global__ void bias_relu_kernel(float* __restrict__ x,
                                 const float* __restrict__ b, int total) {
  int i = blockIdx.x * 256 + threadIdx.x;
  if (i >= total) return;
  x[i] = fmaxf(x[i] + b[i & 127], 0.f);
}

// ---------------- sort pooling ----------------
__global__ __launch_bounds__(64) void row_max_kernel(const float* __restrict__ x,
                                                     float* __restrict__ key) {
  int node = blockIdx.x, lane = threadIdx.x;
  float v = fmaxf(x[(size_t)node * 128 + lane], x[(size_t)node * 128 + 64 + lane]);
#pragma unroll
  for (int off = 32; off; off >>= 1) v = fmaxf(v, __shfl_down(v, off));
  if (lane == 0) key[node] = v;
}

__global__ __launch_bounds__(64) void select_topk_kernel(
    const float* __restrict__ key, int* __restrict__ sel) {
  __shared__ float keys[NPG];
  int g = blockIdx.x, t = threadIdx.x;
  keys[t] = key[(size_t)g * NPG + t];
  __syncthreads();
  float myk = keys[t];
  int rank = 0;
  for (int j = 0; j < NPG; ++j) {
    float kj = keys[j];
    rank += (kj > myk) || (kj == myk && j < t);
  }
  if (rank < KK) sel[g * KK + rank] = t;
}

__global__ __launch_bounds__(128) void sort_rows_kernel(
    const float* __restrict__ x, const int* __restrict__ sel,
    float* __restrict__ xp) {
  __shared__ float v[128];
  int b = blockIdx.x;
  int t = threadIdx.x;
  int g = b >> 3, r = b & 7;
  int node = sel[b];
  v[t] = x[(size_t)(g * NPG + node) * 128 + t];
  __syncthreads();
  for (int k = 2; k <= 128; k <<= 1) {
    for (int j = k >> 1; j > 0; j >>= 1) {
      int ixj = t ^ j;
      if (ixj > t) {
        float a = v[t], bb = v[ixj];
        bool asc = ((t & k) == 0);
        if (asc ? (a > bb) : (a < bb)) { v[t] = bb; v[ixj] = a; }
      }
      __syncthreads();
    }
  }
  xp[(size_t)g * (KK * 128) + r * 128 + t] = v[t];
}

// ---------------- classifier ----------------
__global__ __launch_bounds__(64) void classifier_kernel(
    const float* __restrict__ x, const float* __restrict__ Wc,
    const float* __restrict__ bc, float* __restrict__ out) {
  int g = blockIdx.x, lane = threadIdx.x;
  float v1 = x[(size_t)g * 128 + lane];
  float v2 = x[(size_t)g * 128 + 64 + lane];
  float a0 = v1 * Wc[lane * 2 + 0] + v2 * Wc[(64 + lane) * 2 + 0];
  float a1 = v1 * Wc[lane * 2 + 1] + v2 * Wc[(64 + lane) * 2 + 1];
#pragma unroll
  for (int off = 32; off; off >>= 1) {
    a0 += __shfl_down(a0, off);
    a1 += __shfl_down(a1, off);
  }
  if (lane == 0) {
    out[g * 2 + 0] = a0 + bc[0];
    out[g * 2 + 1] = a1 + bc[1];
  }
}

// ---------------- launcher ----------------
extern "C" void kernel_launch(void* const* d_in, const int* in_sizes, int n_in,
                              void* d_out, int out_size, void* d_ws, size_t ws_size,
                              hipStream_t stream) {
  const size_t BASE_FLOATS = (size_t)NN * DD * 2 + (size_t)NN * 4;  // X,F,el,er,mx,sm
  const size_t CSR_INTS = (size_t)(NN + 1) + NN + EE + 128;          // row_ptr,cursor,adj,part
  if (ws_size < BASE_FLOATS * sizeof(float)) {
    hipMemsetAsync(d_out, 0, (size_t)out_size * sizeof(float), stream);
    return;
  }
  const bool use_csr = ws_size >= BASE_FLOATS * sizeof(float) + CSR_INTS * sizeof(int);

  const int* h      = (const int*)d_in[0];
  const int* g_src  = (const int*)d_in[1];
  const int* g_dst  = (const int*)d_in[2];
  const int* fg_src = (const int*)d_in[3];
  const int* fg_dst = (const int*)d_in[4];
  const float* temb = (const float*)d_in[5];
  const float* W1 = (const float*)d_in[6];
  const float* al1 = (const float*)d_in[7];
  const float* ar1 = (const float*)d_in[8];
  const float* b1 = (const float*)d_in[9];
  const float* W2 = (const float*)d_in[10];
  const float* al2 = (const float*)d_in[11];
  const float* ar2 = (const float*)d_in[12];
  const float* b2 = (const float*)d_in[13];
  const float* W3 = (const float*)d_in[14];
  const float* al3 = (const float*)d_in[15];
  const float* ar3 = (const float*)d_in[16];
  const float* b3 = (const float*)d_in[17];
  const float* Wf = (const float*)d_in[18];
  const float* bfv = (const float*)d_in[19];
  const float* Wl = (const float*)d_in[20];
  const float* bl = (const float*)d_in[21];
  const float* Wl1 = (const float*)d_in[22];
  const float* bl1 = (const float*)d_in[23];
  const float* Wc = (const float*)d_in[24];
  const float* bc = (const float*)d_in[25];
  float* out = (float*)d_out;

  // ---- workspace layout ----
  float* ws = (float*)d_ws;
  float* X  = ws;
  float* F  = X + (size_t)NN * DD;   // used as bf16 (first half) on CSR path
  float* el = F + (size_t)NN * DD;
  float* er = el + NN;
  float* mx = er + NN;
  float* sm = mx + NN;
  int* row_ptr = (int*)(sm + NN);
  int* cursor  = row_ptr + NN + 1;
  int* adj_src = cursor + NN;
  int* part    = adj_src + EE;
  // carved from F once F is dead (after layer-2 aggregation):
  float* xp   = F;
  float* f3   = F + 2097152;
  float* g3   = f3 + (size_t)GG * DD;
  float* t1   = g3 + (size_t)GG * DD;
  float* t2   = t1 + (size_t)GG * DD;
  float* keyb = t2 + (size_t)GG * DD;
  int*   sel  = (int*)(keyb + NN);

  const int totalND = NN * DD;

  if (use_csr) {
    bfu* Fb = (bfu*)F;
    // ---- build CSR of inner graph by dst (reused by both GAT layers) ----
    zero_int_kernel<<<NN / 256, 256, 0, stream>>>(cursor, NN);
    hist_kernel<<<EE / 256, 256, 0, stream>>>(g_dst, cursor, EE);
    scan_block_kernel<<<NN / 1024, 256, 0, stream>>>(cursor, row_ptr, part);
    scan_part_kernel<<<1, 128, 0, stream>>>(part);
    scan_add_kernel<<<(NN + 255) / 256, 256, 0, stream>>>(row_ptr, part, NN, EE);
    zero_int_kernel<<<NN / 256, 256, 0, stream>>>(cursor, NN);
    scatter_kernel<<<EE / 256, 256, 0, stream>>>(g_dst, g_src, row_ptr, cursor, adj_src, EE);

    // layer 1: F(bf16) = relu(temb[h]) @ W1 (MFMA split) + el/er epilogue
    mfma_gemm<1, 1><<<NN / 64, 256, 0, stream>>>(
        nullptr, temb, h, W1, nullptr, Fb, al1, ar1, el, er, nullptr);
    gat_aggregate_csr_kernel<<<NN / 4, 256, 0, stream>>>(Fb, el, er, row_ptr, adj_src, b1, X);

    // layer 2
    mfma_gemm<0, 1><<<NN / 64, 256, 0, stream>>>(
        X, nullptr, nullptr, W2, nullptr, Fb, al2, ar2, el, er, nullptr);
    gat_aggregate_csr_kernel<<<NN / 4, 256, 0, stream>>>(Fb, el, er, row_ptr, adj_src, b2, X);

    // linear_forward in-place + fused row-max
    mfma_gemm<0, 2><<<NN / 64, 256, 0, stream>>>(
        X, nullptr, nullptr, Wf, bfv, X, nullptr, nullptr, nullptr, nullptr, keyb);
  } else {
    embed_relu_kernel<<<totalND / 256, 256, 0, stream>>>(temb, h, X, totalND);
    auto gat_inner = [&](const float* W, const float* al, const float* ar, const float* bb) {
      gemm_kernel<DD, 8><<<NN / 8, 128, 0, stream>>>(X, W, nullptr, F, 0);
      attn_logits_kernel<<<NN, 64, 0, stream>>>(F, al, ar, el, er);
      init_softmax_kernel<<<(NN + 255) / 256, 256, 0, stream>>>(mx, sm, NN);
      fill_f32_kernel<<<totalND / 256, 256, 0, stream>>>(X, 0.f, totalND);
      edge_max_kernel<<<(EE + 255) / 256, 256, 0, stream>>>(el, er, g_src, g_dst, mx, EE);
      edge_expsum_kernel<<<(EE + 255) / 256, 256, 0, stream>>>(el, er, mx, g_src, g_dst, sm, EE);
      edge_aggregate_kernel<<<EE, 128, 0, stream>>>(F, el, er, mx, sm, g_src, g_dst, X, EE);
      bias_relu_kernel<<<totalND / 256, 256, 0, stream>>>(X, bb, totalND);
    };
    gat_inner(W1, al1, ar1, b1);
    gat_inner(W2, al2, ar2, b2);
    gemm_kernel<DD, 8><<<NN / 8, 128, 0, stream>>>(X, Wf, bfv, X, 1);
    row_max_kernel<<<NN, 64, 0, stream>>>(X, keyb);
  }

  // sort pooling -> xp [G, 1024]
  select_topk_kernel<<<GG, 64, 0, stream>>>(keyb, sel);
  sort_rows_kernel<<<GG * KK, 128, 0, stream>>>(X, sel, xp);

  // outer GAT over fg (atomic path — small)
  gemm1024_kernel<<<GG / 8, 256, 0, stream>>>(xp, W3, f3);
  attn_logits_kernel<<<GG, 64, 0, stream>>>(f3, al3, ar3, el, er);
  init_softmax_kernel<<<(GG + 255) / 256, 256, 0, stream>>>(mx, sm, GG);
  fill_f32_kernel<<<(GG * DD + 255) / 256, 256, 0, stream>>>(g3, 0.f, GG * DD);
  edge_max_kernel<<<(EFN + 255) / 256, 256, 0, stream>>>(el, er, fg_src, fg_dst, mx, EFN);
  edge_expsum_kernel<<<(EFN + 255) / 256, 256, 0, stream>>>(el, er, mx, fg_src, fg_dst, sm, EFN);
  edge_aggregate_kernel<<<EFN, 128, 0, stream>>>(f3, el, er, mx, sm, fg_src, fg_dst, g3, EFN);
  bias_relu_kernel<<<(GG * DD + 255) / 256, 256, 0, stream>>>(g3, b3, GG * DD);

  // t1 = relu(g3 @ Wl + bl); t2 = relu(t1 @ Wl1 + bl1)
  gemm_kernel<DD, 8><<<GG / 8, 128, 0, stream>>>(g3, Wl, bl, t1, 1);
  gemm_kernel<DD, 8><<<GG / 8, 128, 0, stream>>>(t1, Wl1, bl1, t2, 1);

  // classifier -> fp32 out [G,2]
  classifier_kernel<<<GG, 64, 0, stream>>>(t2, Wc, bc, out);
}

// Round 15
// 568.302 us; speedup vs baseline: 1.2036x; 1.2036x over previous
//
#include <hip/hip_runtime.h>
#include <math.h>

#define NN   131072   // total inner nodes
#define GG   2048     // graphs
#define NPG  64       // nodes per graph
#define EE   1048576  // inner edges
#define EFN  32768    // outer edges
#define DD   128      // feature dim
#define KK   8        // sortpool k

typedef unsigned short bfu;  // raw bf16 bits
typedef short bf16x8 __attribute__((ext_vector_type(8)));
typedef float f32x4 __attribute__((ext_vector_type(4)));

static __device__ __forceinline__ bfu f2b(float f) {  // RNE f32 -> bf16
  unsigned u = __float_as_uint(f);
  u += 0x7FFFu + ((u >> 16) & 1u);
  return (bfu)(u >> 16);
}
static __device__ __forceinline__ float b2f(bfu b) {
  return __uint_as_float(((unsigned)b) << 16);
}

// ---------------- utility ----------------
__global__ void fill_f32_kernel(float* __restrict__ p, float v, int nElems) {
  int i = blockIdx.x * 256 + threadIdx.x;
  if (i < nElems) p[i] = v;
}

__global__ void zero_int_kernel(int* __restrict__ p, int nElems) {
  int i = blockIdx.x * 256 + threadIdx.x;
  if (i < nElems) p[i] = 0;
}

__global__ void init_softmax_kernel(float* __restrict__ mx, float* __restrict__ sm, int nElems) {
  int i = blockIdx.x * 256 + threadIdx.x;
  if (i < nElems) { mx[i] = -INFINITY; sm[i] = 0.f; }
}

// x[i] = relu(token_emb[h[node]][d])   (fallback path only)
__global__ void embed_relu_kernel(const float* __restrict__ temb,
                                  const int* __restrict__ h,
                                  float* __restrict__ x, int total) {
  int i = blockIdx.x * 256 + threadIdx.x;
  if (i >= total) return;
  int node = i >> 7, d = i & 127;
  x[i] = fmaxf(temb[h[node] * DD + d], 0.f);
}

// ---------------- small / generic GEMM (outer graph, fallback) ----------------
template <int KD, int ROWS>
__global__ __launch_bounds__(128) void gemm_kernel(
    const float* __restrict__ A, const float* __restrict__ W,
    const float* __restrict__ bias, float* __restrict__ out,
    int relu_flag) {
  __shared__ float As[ROWS * KD];
  const int row0 = blockIdx.x * ROWS;
  const int tid = threadIdx.x;
  for (int i = tid; i < ROWS * KD; i += 128) As[i] = A[(size_t)row0 * KD + i];
  __syncthreads();
  float acc[ROWS];
#pragma unroll
  for (int r = 0; r < ROWS; r++) acc[r] = 0.f;
  for (int k = 0; k < KD; k++) {
    float w = W[k * 128 + tid];
#pragma unroll
    for (int r = 0; r < ROWS; r++) acc[r] += As[r * KD + k] * w;
  }
  float b = bias ? bias[tid] : 0.f;
#pragma unroll
  for (int r = 0; r < ROWS; r++) {
    float v = acc[r] + b;
    if (relu_flag) v = fmaxf(v, 0.f);
    out[(size_t)(row0 + r) * 128 + tid] = v;
  }
}

// ---------------- outer-GAT GEMM: f3[G,128] = xp[G,1024] @ W3[1024,128] ----------------
__global__ __launch_bounds__(256) void gemm1024_kernel(
    const float* __restrict__ A, const float* __restrict__ W,
    float* __restrict__ out) {
  __shared__ float As[8 * 1024];
  __shared__ float red[8][256];
  const int t = threadIdx.x;
  const int row0 = blockIdx.x * 8;
  for (int idx = t; idx < 8 * 256; idx += 256) {
    int r = idx >> 8, c4 = (idx & 255) << 2;
    *(float4*)&As[r * 1024 + c4] = *(const float4*)(A + (size_t)(row0 + r) * 1024 + c4);
  }
  __syncthreads();
  const int col = t & 127, kh = t >> 7;
  const int k0 = kh * 512;
  float acc[8];
#pragma unroll
  for (int r = 0; r < 8; r++) acc[r] = 0.f;
  for (int k = k0; k < k0 + 512; k += 4) {
    float w0 = W[(size_t)(k + 0) * 128 + col];
    float w1 = W[(size_t)(k + 1) * 128 + col];
    float w2 = W[(size_t)(k + 2) * 128 + col];
    float w3 = W[(size_t)(k + 3) * 128 + col];
#pragma unroll
    for (int r = 0; r < 8; r++) {
      float4 a = *(const float4*)&As[r * 1024 + k];
      acc[r] += a.x * w0 + a.y * w1 + a.z * w2 + a.w * w3;
    }
  }
#pragma unroll
  for (int r = 0; r < 8; r++) red[r][t] = acc[r];
  __syncthreads();
  for (int idx = t; idx < 1024; idx += 256) {
    int r = idx >> 7, c = idx & 127;
    out[(size_t)(row0 + r) * 128 + c] = red[r][c] + red[r][128 + c];
  }
}

// ---------------- W pack: fragment-ordered split-bf16 table ----------------
// W[k][n] (128x128 fp32) -> hi/lo tables indexed [kk][tt][quad][m16][j]:
// lane (quad,m16) at (kk,tt) reads 8 consecutive bf16 = B[k=kk*32+quad*8+j][n=tt*16+m16].
__global__ void pack_w_kernel(const float* __restrict__ W,
                              bfu* __restrict__ hi, bfu* __restrict__ lo) {
  int i = blockIdx.x * 256 + threadIdx.x;  // 0..16383
  if (i >= 16384) return;
  int k = i >> 7, n = i & 127;
  float w = W[i];
  bfu h = f2b(w);
  bfu l = f2b(w - b2f(h));
  int kk = k >> 5, k5 = k & 31, quad = k5 >> 3, j = k5 & 7;
  int tt = n >> 4, m16 = n & 15;
  int pos = ((((kk * 8 + tt) * 4 + quad) * 16) + m16) * 8 + j;
  hi[pos] = h;
  lo[pos] = l;
}

// ---------------- MFMA split-precision GEMM (LDS-free) ----------------
// 3-term bf16 split (A_hi*W_hi + A_hi*W_lo + A_lo*W_hi) ~ fp32 accuracy.
// B fragments read directly from the packed global tables (L2-resident 64KB,
// coalesced 16B/lane) — no LDS, no barriers, no bank conflicts.
// 256 thr = 4 waves x 16 rows. Fragment layouts (verified r13/r14):
//   A: m=lane&15, k=quad*8+j ; C/D: col=lane&15, row=quad*4+reg.
template <int SRC_MODE, int EPI>
__global__ __launch_bounds__(256) void mfma_gemm(
    const float* A, const float* __restrict__ temb,
    const int* __restrict__ hidx,
    const bfu* __restrict__ WfHi, const bfu* __restrict__ WfLo,
    const float* __restrict__ bias, void* out,
    const float* __restrict__ al, const float* __restrict__ ar,
    float* __restrict__ el, float* __restrict__ er,
    float* __restrict__ keyb) {
  const int t = threadIdx.x;
  const int lane = t & 63, wv_ = t >> 6;
  const int m16 = lane & 15, quad = lane >> 4;
  const int rowbase = blockIdx.x * 64 + wv_ * 16;
  const int grow = rowbase + m16;
  const float* arow = (SRC_MODE == 1) ? (temb + (size_t)hidx[grow] * 128)
                                      : (A + (size_t)grow * 128);
  f32x4 acc[8];
#pragma unroll
  for (int i = 0; i < 8; i++) acc[i] = (f32x4){0.f, 0.f, 0.f, 0.f};
#pragma unroll
  for (int kk = 0; kk < 4; kk++) {
    int k0 = kk * 32 + quad * 8;
    float av[8];
    *(float4*)&av[0] = *(const float4*)(arow + k0);
    *(float4*)&av[4] = *(const float4*)(arow + k0 + 4);
    if (SRC_MODE == 1) {
#pragma unroll
      for (int i = 0; i < 8; i++) av[i] = fmaxf(av[i], 0.f);
    }
    bf16x8 ahi, alo;
#pragma unroll
    for (int i = 0; i < 8; i++) {
      bfu hi = f2b(av[i]);
      bfu lo = f2b(av[i] - b2f(hi));
      ahi[i] = (short)hi;
      alo[i] = (short)lo;
    }
#pragma unroll
    for (int tt = 0; tt < 8; tt++) {
      int pos = ((((kk * 8 + tt) * 4 + quad) * 16) + m16) * 8;
      bf16x8 bhi = *(const bf16x8*)&WfHi[pos];
      bf16x8 blo = *(const bf16x8*)&WfLo[pos];
      acc[tt] = __builtin_amdgcn_mfma_f32_16x16x32_bf16(ahi, bhi, acc[tt], 0, 0, 0);
      acc[tt] = __builtin_amdgcn_mfma_f32_16x16x32_bf16(ahi, blo, acc[tt], 0, 0, 0);
      acc[tt] = __builtin_amdgcn_mfma_f32_16x16x32_bf16(alo, bhi, acc[tt], 0, 0, 0);
    }
  }
  // epilogue: lane holds D[row=rowbase+quad*4+r][col=tt*16+m16]
  if (EPI == 1) {
    float pl[4] = {0.f, 0.f, 0.f, 0.f}, pr[4] = {0.f, 0.f, 0.f, 0.f};
#pragma unroll
    for (int tt = 0; tt < 8; tt++) {
      int col = tt * 16 + m16;
      float alv = al[col], arv = ar[col];
#pragma unroll
      for (int r = 0; r < 4; r++) {
        float v = acc[tt][r];
        ((bfu*)out)[(size_t)(rowbase + quad * 4 + r) * 128 + col] = f2b(v);
        pl[r] += v * alv;
        pr[r] += v * arv;
      }
    }
#pragma unroll
    for (int r = 0; r < 4; r++) {
      float a0 = pl[r], a1 = pr[r];
#pragma unroll
      for (int off = 1; off < 16; off <<= 1) {
        a0 += __shfl_xor(a0, off);
        a1 += __shfl_xor(a1, off);
      }
      if (m16 == 0) {
        el[rowbase + quad * 4 + r] = a0;
        er[rowbase + quad * 4 + r] = a1;
      }
    }
  } else {  // EPI == 2
    float pm[4] = {-INFINITY, -INFINITY, -INFINITY, -INFINITY};
#pragma unroll
    for (int tt = 0; tt < 8; tt++) {
      int col = tt * 16 + m16;
      float bv = bias[col];
#pragma unroll
      for (int r = 0; r < 4; r++) {
        float v = fmaxf(acc[tt][r] + bv, 0.f);
        ((float*)out)[(size_t)(rowbase + quad * 4 + r) * 128 + col] = v;
        pm[r] = fmaxf(pm[r], v);
      }
    }
#pragma unroll
    for (int r = 0; r < 4; r++) {
      float a0 = pm[r];
#pragma unroll
      for (int off = 1; off < 16; off <<= 1) a0 = fmaxf(a0, __shfl_xor(a0, off));
      if (m16 == 0) keyb[rowbase + quad * 4 + r] = a0;
    }
  }
}

// ---------------- attention logits (outer graph, fallback) ----------------
__global__ __launch_bounds__(64) void attn_logits_kernel(
    const float* __restrict__ f, const float* __restrict__ al,
    const float* __restrict__ ar, float* __restrict__ el,
    float* __restrict__ er) {
  int node = blockIdx.x, lane = threadIdx.x;
  float v1 = f[(size_t)node * 128 + lane];
  float v2 = f[(size_t)node * 128 + 64 + lane];
  float sl = v1 * al[lane] + v2 * al[64 + lane];
  float sr = v1 * ar[lane] + v2 * ar[64 + lane];
#pragma unroll
  for (int off = 32; off; off >>= 1) {
    sl += __shfl_down(sl, off);
    sr += __shfl_down(sr, off);
  }
  if (lane == 0) { el[node] = sl; er[node] = sr; }
}

// ---------------- CSR build ----------------
__global__ void hist_kernel(const int* __restrict__ dst, int* __restrict__ cnt, int nE) {
  int e = blockIdx.x * 256 + threadIdx.x;
  if (e < nE) atomicAdd(&cnt[dst[e]], 1);
}

__global__ __launch_bounds__(256) void scan_block_kernel(
    const int* __restrict__ cnt, int* __restrict__ excl, int* __restrict__ part) {
  __shared__ int s[256];
  int blk = blockIdx.x, tid = threadIdx.x;
  int base = blk * 1024 + tid * 4;
  int a0 = cnt[base], a1 = cnt[base + 1], a2 = cnt[base + 2], a3 = cnt[base + 3];
  int tsum = a0 + a1 + a2 + a3;
  s[tid] = tsum; __syncthreads();
  for (int off = 1; off < 256; off <<= 1) {
    int v = (tid >= off) ? s[tid - off] : 0;
    __syncthreads();
    s[tid] += v;
    __syncthreads();
  }
  int texcl = s[tid] - tsum;
  excl[base]     = texcl;
  excl[base + 1] = texcl + a0;
  excl[base + 2] = texcl + a0 + a1;
  excl[base + 3] = texcl + a0 + a1 + a2;
  if (tid == 255) part[blk] = s[255];
}

__global__ __launch_bounds__(128) void scan_part_kernel(int* __restrict__ part) {
  __shared__ int s[128];
  int tid = threadIdx.x;
  int orig = part[tid];
  s[tid] = orig; __syncthreads();
  for (int off = 1; off < 128; off <<= 1) {
    int v = (tid >= off) ? s[tid - off] : 0;
    __syncthreads();
    s[tid] += v;
    __syncthreads();
  }
  part[tid] = s[tid] - orig;
}

__global__ void scan_add_kernel(int* __restrict__ row_ptr, const int* __restrict__ part,
                                int n, int total) {
  int i = blockIdx.x * 256 + threadIdx.x;
  if (i < n) row_ptr[i] += part[i >> 10];
  if (i == 0) row_ptr[n] = total;
}

__global__ void scatter_kernel(const int* __restrict__ dst, const int* __restrict__ src,
                               const int* __restrict__ row_ptr,
                               int* __restrict__ cursor, int* __restrict__ adj_src, int nE) {
  int e = blockIdx.x * 256 + threadIdx.x;
  if (e >= nE) return;
  int d = dst[e];
  int pos = row_ptr[d] + atomicAdd(&cursor[d], 1);
  adj_src[pos] = src[e];
}

// ---------------- fused CSR GAT aggregation: one 64-lane wave per dst ----------------
__global__ __launch_bounds__(256) void gat_aggregate_csr_kernel(
    const bfu* __restrict__ F, const float* __restrict__ el,
    const float* __restrict__ er, const int* __restrict__ row_ptr,
    const int* __restrict__ adj_src,
    const float* __restrict__ bias, float* __restrict__ outX) {
  const int lane = threadIdx.x & 63;
  const int d = blockIdx.x * 4 + (threadIdx.x >> 6);
  const int c0 = lane * 2;
  int beg = row_ptr[d];
  int n = row_ptr[d + 1] - beg;
  float2 bv = *(const float2*)&bias[c0];
  if (n == 0) {
    float2 o; o.x = fmaxf(bv.x, 0.f); o.y = fmaxf(bv.y, 0.f);
    *(float2*)&outX[(size_t)d * 128 + c0] = o;
    return;
  }
  float er_d = er[d];
  float2 acc = make_float2(0.f, 0.f);
  if (n <= 64) {
    int sv = 0; float sc = -INFINITY;
    if (lane < n) {
      sv = adj_src[beg + lane];
      float v = el[sv] + er_d;
      sc = v > 0.f ? v : 0.2f * v;
    }
    float m = sc;
#pragma unroll
    for (int off = 32; off; off >>= 1) m = fmaxf(m, __shfl_xor(m, off));
    float ex = (lane < n) ? expf(sc - m) : 0.f;
    float s = ex;
#pragma unroll
    for (int off = 32; off; off >>= 1) s += __shfl_xor(s, off);
    float wt = ex / s;
    for (int j = 0; j < n; j += 4) {
      int   s0 = __shfl(sv, j);
      float w0 = __shfl(wt, j);
      int   j1 = (j + 1 < n) ? j + 1 : j;
      int   s1 = __shfl(sv, j1); float w1 = (j + 1 < n) ? __shfl(wt, j1) : 0.f;
      int   j2 = (j + 2 < n) ? j + 2 : j;
      int   s2 = __shfl(sv, j2); float w2 = (j + 2 < n) ? __shfl(wt, j2) : 0.f;
      int   j3 = (j + 3 < n) ? j + 3 : j;
      int   s3 = __shfl(sv, j3); float w3 = (j + 3 < n) ? __shfl(wt, j3) : 0.f;
      ushort2 f0 = *(const ushort2*)&F[(size_t)s0 * 128 + c0];
      ushort2 f1 = *(const ushort2*)&F[(size_t)s1 * 128 + c0];
      ushort2 f2 = *(const ushort2*)&F[(size_t)s2 * 128 + c0];
      ushort2 f3 = *(const ushort2*)&F[(size_t)s3 * 128 + c0];
      acc.x += w0 * b2f(f0.x) + w1 * b2f(f1.x) + w2 * b2f(f2.x) + w3 * b2f(f3.x);
      acc.y += w0 * b2f(f0.y) + w1 * b2f(f1.y) + w2 * b2f(f2.y) + w3 * b2f(f3.y);
    }
  } else {
    float lm = -INFINITY;
    for (int t = lane; t < n; t += 64) {
      int sv = adj_src[beg + t];
      float v = el[sv] + er_d;
      v = v > 0.f ? v : 0.2f * v;
      lm = fmaxf(lm, v);
    }
#pragma unroll
    for (int off = 32; off; off >>= 1) lm = fmaxf(lm, __shfl_xor(lm, off));
    float ls = 0.f;
    for (int t = lane; t < n; t += 64) {
      int sv = adj_src[beg + t];
      float v = el[sv] + er_d;
      v = v > 0.f ? v : 0.2f * v;
      ls += expf(v - lm);
    }
#pragma unroll
    for (int off = 32; off; off >>= 1) ls += __shfl_xor(ls, off);
    for (int base = 0; base < n; base += 64) {
      int t = base + lane;
      int sv = 0; float wt = 0.f;
      if (t < n) {
        sv = adj_src[beg + t];
        float v = el[sv] + er_d;
        v = v > 0.f ? v : 0.2f * v;
        wt = expf(v - lm) / ls;
      }
      int cnt = min(64, n - base);
      for (int j = 0; j < cnt; ++j) {
        int s0 = __shfl(sv, j);
        float w0 = __shfl(wt, j);
        ushort2 f0 = *(const ushort2*)&F[(size_t)s0 * 128 + c0];
        acc.x += w0 * b2f(f0.x);
        acc.y += w0 * b2f(f0.y);
      }
    }
  }
  float2 o;
  o.x = fmaxf(acc.x + bv.x, 0.f);
  o.y = fmaxf(acc.y + bv.y, 0.f);
  *(float2*)&outX[(size_t)d * 128 + c0] = o;
}

// ---------------- atomic-path edge kernels (outer graph + fallback) ----------------
static __device__ __forceinline__ void atomicMaxF(float* addr, float v) {
  int iv = __float_as_int(v);
  if (iv >= 0) atomicMax((int*)addr, iv);
  else atomicMin((unsigned int*)addr, (unsigned int)iv);
}

static __device__ __forceinline__ float edge_score(const float* el, const float* er,
                                                   int sv, int dv) {
  float v = el[sv] + er[dv];
  return v > 0.f ? v : 0.2f * v;
}

__global__ void edge_max_kernel(const float* __restrict__ el,
                                const float* __restrict__ er,
                                const int* __restrict__ src,
                                const int* __restrict__ dst,
                                float* __restrict__ m, int nE) {
  int e = blockIdx.x * 256 + threadIdx.x;
  if (e >= nE) return;
  atomicMaxF(&m[dst[e]], edge_score(el, er, src[e], dst[e]));
}

__global__ void edge_expsum_kernel(const float* __restrict__ el,
                                   const float* __restrict__ er,
                                   const float* __restrict__ m,
                                   const int* __restrict__ src,
                                   const int* __restrict__ dst,
                                   float* __restrict__ s, int nE) {
  int e = blockIdx.x * 256 + threadIdx.x;
  if (e >= nE) return;
  int d = dst[e];
  atomicAdd(&s[d], expf(edge_score(el, er, src[e], d) - m[d]));
}

__global__ __launch_bounds__(128) void edge_aggregate_kernel(
    const float* __restrict__ f, const float* __restrict__ el,
    const float* __restrict__ er, const float* __restrict__ m,
    const float* __restrict__ s, const int* __restrict__ src,
    const int* __restrict__ dst, float* __restrict__ out, int nE) {
  int e = blockIdx.x;
  int d = threadIdx.x;
  int sv = src[e], dv = dst[e];
  float alpha = expf(edge_score(el, er, sv, dv) - m[dv]) / s[dv];
  atomicAdd(&out[(size_t)dv * 128 + d], alpha * f[(size_t)sv * 128 + d]);
}

__global__ void bias_relu_kernel(float* __restrict__ x,
                                 const float* __restrict__ b, int total) {
  int i = blockIdx.x * 256 + threadIdx.x;
  if (i >= total) return;
  x[i] = fmaxf(x[i] + b[i & 127], 0.f);
}

// ---------------- sort pooling ----------------
__global__ __launch_bounds__(64) void row_max_kernel(const float* __restrict__ x,
                                                     float* __restrict__ key) {
  int node = blockIdx.x, lane = threadIdx.x;
  float v = fmaxf(x[(size_t)node * 128 + lane], x[(size_t)node * 128 + 64 + lane]);
#pragma unroll
  for (int off = 32; off; off >>= 1) v = fmaxf(v, __shfl_down(v, off));
  if (lane == 0) key[node] = v;
}

__global__ __launch_bounds__(64) void select_topk_kernel(
    const float* __restrict__ key, int* __restrict__ sel) {
  __shared__ float keys[NPG];
  int g = blockIdx.x, t = threadIdx.x;
  keys[t] = key[(size_t)g * NPG + t];
  __syncthreads();
  float myk = keys[t];
  int rank = 0;
  for (int j = 0; j < NPG; ++j) {
    float kj = keys[j];
    rank += (kj > myk) || (kj == myk && j < t);
  }
  if (rank < KK) sel[g * KK + rank] = t;
}

__global__ __launch_bounds__(128) void sort_rows_kernel(
    const float* __restrict__ x, const int* __restrict__ sel,
    float* __restrict__ xp) {
  __shared__ float v[128];
  int b = blockIdx.x;
  int t = threadIdx.x;
  int g = b >> 3, r = b & 7;
  int node = sel[b];
  v[t] = x[(size_t)(g * NPG + node) * 128 + t];
  __syncthreads();
  for (int k = 2; k <= 128; k <<= 1) {
    for (int j = k >> 1; j > 0; j >>= 1) {
      int ixj = t ^ j;
      if (ixj > t) {
        float a = v[t], bb = v[ixj];
        bool asc = ((t & k) == 0);
        if (asc ? (a > bb) : (a < bb)) { v[t] = bb; v[ixj] = a; }
      }
      __syncthreads();
    }
  }
  xp[(size_t)g * (KK * 128) + r * 128 + t] = v[t];
}

// ---------------- classifier ----------------
__global__ __launch_bounds__(64) void classifier_kernel(
    const float* __restrict__ x, const float* __restrict__ Wc,
    const float* __restrict__ bc, float* __restrict__ out) {
  int g = blockIdx.x, lane = threadIdx.x;
  float v1 = x[(size_t)g * 128 + lane];
  float v2 = x[(size_t)g * 128 + 64 + lane];
  float a0 = v1 * Wc[lane * 2 + 0] + v2 * Wc[(64 + lane) * 2 + 0];
  float a1 = v1 * Wc[lane * 2 + 1] + v2 * Wc[(64 + lane) * 2 + 1];
#pragma unroll
  for (int off = 32; off; off >>= 1) {
    a0 += __shfl_down(a0, off);
    a1 += __shfl_down(a1, off);
  }
  if (lane == 0) {
    out[g * 2 + 0] = a0 + bc[0];
    out[g * 2 + 1] = a1 + bc[1];
  }
}

// ---------------- launcher ----------------
extern "C" void kernel_launch(void* const* d_in, const int* in_sizes, int n_in,
                              void* d_out, int out_size, void* d_ws, size_t ws_size,
                              hipStream_t stream) {
  const size_t BASE_FLOATS = (size_t)NN * DD * 2 + (size_t)NN * 4;  // X,F,el,er,mx,sm
  const size_t CSR_INTS = (size_t)(NN + 1) + NN + EE + 128;          // row_ptr,cursor,adj,part
  if (ws_size < BASE_FLOATS * sizeof(float)) {
    hipMemsetAsync(d_out, 0, (size_t)out_size * sizeof(float), stream);
    return;
  }
  const bool use_csr = ws_size >= BASE_FLOATS * sizeof(float) + CSR_INTS * sizeof(int);

  const int* h      = (const int*)d_in[0];
  const int* g_src  = (const int*)d_in[1];
  const int* g_dst  = (const int*)d_in[2];
  const int* fg_src = (const int*)d_in[3];
  const int* fg_dst = (const int*)d_in[4];
  const float* temb = (const float*)d_in[5];
  const float* W1 = (const float*)d_in[6];
  const float* al1 = (const float*)d_in[7];
  const float* ar1 = (const float*)d_in[8];
  const float* b1 = (const float*)d_in[9];
  const float* W2 = (const float*)d_in[10];
  const float* al2 = (const float*)d_in[11];
  const float* ar2 = (const float*)d_in[12];
  const float* b2 = (const float*)d_in[13];
  const float* W3 = (const float*)d_in[14];
  const float* al3 = (const float*)d_in[15];
  const float* ar3 = (const float*)d_in[16];
  const float* b3 = (const float*)d_in[17];
  const float* Wf = (const float*)d_in[18];
  const float* bfv = (const float*)d_in[19];
  const float* Wl = (const float*)d_in[20];
  const float* bl = (const float*)d_in[21];
  const float* Wl1 = (const float*)d_in[22];
  const float* bl1 = (const float*)d_in[23];
  const float* Wc = (const float*)d_in[24];
  const float* bc = (const float*)d_in[25];
  float* out = (float*)d_out;

  // ---- workspace layout ----
  float* ws = (float*)d_ws;
  float* X  = ws;
  float* F  = X + (size_t)NN * DD;   // used as bf16 (first half) on CSR path
  float* el = F + (size_t)NN * DD;
  float* er = el + NN;
  float* mx = er + NN;
  float* sm = mx + NN;
  int* row_ptr = (int*)(sm + NN);
  int* cursor  = row_ptr + NN + 1;
  int* adj_src = cursor + NN;
  int* part    = adj_src + EE;
  // packed W tables live in mx/sm (unused by CSR-path inner layers):
  bfu* w1h = (bfu*)mx;            // 16384 each
  bfu* w1l = w1h + 16384;
  bfu* w2h = w1l + 16384;
  bfu* w2l = w2h + 16384;
  bfu* wfh = w2l + 16384;
  bfu* wfl = wfh + 16384;          // total 192KB < 512KB (mx region alone)
  // carved from F once F is dead (after layer-2 aggregation):
  float* xp   = F;
  float* f3   = F + 2097152;
  float* g3   = f3 + (size_t)GG * DD;
  float* t1   = g3 + (size_t)GG * DD;
  float* t2   = t1 + (size_t)GG * DD;
  float* keyb = t2 + (size_t)GG * DD;
  int*   sel  = (int*)(keyb + NN);

  const int totalND = NN * DD;

  if (use_csr) {
    bfu* Fb = (bfu*)F;
    // ---- build CSR of inner graph by dst (reused by both GAT layers) ----
    zero_int_kernel<<<NN / 256, 256, 0, stream>>>(cursor, NN);
    hist_kernel<<<EE / 256, 256, 0, stream>>>(g_dst, cursor, EE);
    scan_block_kernel<<<NN / 1024, 256, 0, stream>>>(cursor, row_ptr, part);
    scan_part_kernel<<<1, 128, 0, stream>>>(part);
    scan_add_kernel<<<(NN + 255) / 256, 256, 0, stream>>>(row_ptr, part, NN, EE);
    zero_int_kernel<<<NN / 256, 256, 0, stream>>>(cursor, NN);
    scatter_kernel<<<EE / 256, 256, 0, stream>>>(g_dst, g_src, row_ptr, cursor, adj_src, EE);

    // pack the three 128x128 weights into fragment-ordered split tables
    pack_w_kernel<<<64, 256, 0, stream>>>(W1, w1h, w1l);
    pack_w_kernel<<<64, 256, 0, stream>>>(W2, w2h, w2l);
    pack_w_kernel<<<64, 256, 0, stream>>>(Wf, wfh, wfl);

    // layer 1: F(bf16) = relu(temb[h]) @ W1 (MFMA split) + el/er epilogue
    mfma_gemm<1, 1><<<NN / 64, 256, 0, stream>>>(
        nullptr, temb, h, w1h, w1l, nullptr, Fb, al1, ar1, el, er, nullptr);
    gat_aggregate_csr_kernel<<<NN / 4, 256, 0, stream>>>(Fb, el, er, row_ptr, adj_src, b1, X);

    // layer 2
    mfma_gemm<0, 1><<<NN / 64, 256, 0, stream>>>(
        X, nullptr, nullptr, w2h, w2l, nullptr, Fb, al2, ar2, el, er, nullptr);
    gat_aggregate_csr_kernel<<<NN / 4, 256, 0, stream>>>(Fb, el, er, row_ptr, adj_src, b2, X);

    // linear_forward in-place + fused row-max
    mfma_gemm<0, 2><<<NN / 64, 256, 0, stream>>>(
        X, nullptr, nullptr, wfh, wfl, bfv, X, nullptr, nullptr, nullptr, nullptr, keyb);
  } else {
    embed_relu_kernel<<<totalND / 256, 256, 0, stream>>>(temb, h, X, totalND);
    auto gat_inner = [&](const float* W, const float* al, const float* ar, const float* bb) {
      gemm_kernel<DD, 8><<<NN / 8, 128, 0, stream>>>(X, W, nullptr, F, 0);
      attn_logits_kernel<<<NN, 64, 0, stream>>>(F, al, ar, el, er);
      init_softmax_kernel<<<(NN + 255) / 256, 256, 0, stream>>>(mx, sm, NN);
      fill_f32_kernel<<<totalND / 256, 256, 0, stream>>>(X, 0.f, totalND);
      edge_max_kernel<<<(EE + 255) / 256, 256, 0, stream>>>(el, er, g_src, g_dst, mx, EE);
      edge_expsum_kernel<<<(EE + 255) / 256, 256, 0, stream>>>(el, er, mx, g_src, g_dst, sm, EE);
      edge_aggregate_kernel<<<EE, 128, 0, stream>>>(F, el, er, mx, sm, g_src, g_dst, X, EE);
      bias_relu_kernel<<<totalND / 256, 256, 0, stream>>>(X, bb, totalND);
    };
    gat_inner(W1, al1, ar1, b1);
    gat_inner(W2, al2, ar2, b2);
    gemm_kernel<DD, 8><<<NN / 8, 128, 0, stream>>>(X, Wf, bfv, X, 1);
    row_max_kernel<<<NN, 64, 0, stream>>>(X, keyb);
  }

  // sort pooling -> xp [G, 1024]
  select_topk_kernel<<<GG, 64, 0, stream>>>(keyb, sel);
  sort_rows_kernel<<<GG * KK, 128, 0, stream>>>(X, sel, xp);

  // outer GAT over fg (atomic path — small)
  gemm1024_kernel<<<GG / 8, 256, 0, stream>>>(xp, W3, f3);
  attn_logits_kernel<<<GG, 64, 0, stream>>>(f3, al3, ar3, el, er);
  init_softmax_kernel<<<(GG + 255) / 256, 256, 0, stream>>>(mx, sm, GG);
  fill_f32_kernel<<<(GG * DD + 255) / 256, 256, 0, stream>>>(g3, 0.f, GG * DD);
  edge_max_kernel<<<(EFN + 255) / 256, 256, 0, stream>>>(el, er, fg_src, fg_dst, mx, EFN);
  edge_expsum_kernel<<<(EFN + 255) / 256, 256, 0, stream>>>(el, er, mx, fg_src, fg_dst, sm, EFN);
  edge_aggregate_kernel<<<EFN, 128, 0, stream>>>(f3, el, er, mx, sm, fg_src, fg_dst, g3, EFN);
  bias_relu_kernel<<<(GG * DD + 255) / 256, 256, 0, stream>>>(g3, b3, GG * DD);

  // t1 = relu(g3 @ Wl + bl); t2 = relu(t1 @ Wl1 + bl1)
  gemm_kernel<DD, 8><<<GG / 8, 128, 0, stream>>>(g3, Wl, bl, t1, 1);
  gemm_kernel<DD, 8><<<GG / 8, 128, 0, stream>>>(t1, Wl1, bl1, t2, 1);

  // classifier -> fp32 out [G,2]
  classifier_kernel<<<GG, 64, 0, stream>>>(t2, Wc, bc, out);
}

// Round 16
// 527.087 us; speedup vs baseline: 1.2977x; 1.0782x over previous
//
#include <hip/hip_runtime.h>
#include <math.h>

#define NN   131072   // total inner nodes
#define GG   2048     // graphs
#define NPG  64       // nodes per graph
#define EE   1048576  // inner edges
#define EFN  32768    // outer edges
#define DD   128      // feature dim
#define KK   8        // sortpool k

typedef unsigned short bfu;  // raw bf16 bits
typedef short bf16x8 __attribute__((ext_vector_type(8)));
typedef float f32x4 __attribute__((ext_vector_type(4)));

static __device__ __forceinline__ bfu f2b(float f) {  // RNE f32 -> bf16
  unsigned u = __float_as_uint(f);
  u += 0x7FFFu + ((u >> 16) & 1u);
  return (bfu)(u >> 16);
}
static __device__ __forceinline__ float b2f(bfu b) {
  return __uint_as_float(((unsigned)b) << 16);
}

// ---------------- utility ----------------
__global__ void fill_f32_kernel(float* __restrict__ p, float v, int nElems) {
  int i = blockIdx.x * 256 + threadIdx.x;
  if (i < nElems) p[i] = v;
}

__global__ void zero_int_kernel(int* __restrict__ p, int nElems) {
  int i = blockIdx.x * 256 + threadIdx.x;
  if (i < nElems) p[i] = 0;
}

__global__ void init_softmax_kernel(float* __restrict__ mx, float* __restrict__ sm, int nElems) {
  int i = blockIdx.x * 256 + threadIdx.x;
  if (i < nElems) { mx[i] = -INFINITY; sm[i] = 0.f; }
}

// x[i] = relu(token_emb[h[node]][d])   (fallback path only)
__global__ void embed_relu_kernel(const float* __restrict__ temb,
                                  const int* __restrict__ h,
                                  float* __restrict__ x, int total) {
  int i = blockIdx.x * 256 + threadIdx.x;
  if (i >= total) return;
  int node = i >> 7, d = i & 127;
  x[i] = fmaxf(temb[h[node] * DD + d], 0.f);
}

// ---------------- small / generic GEMM (outer graph, fallback) ----------------
template <int KD, int ROWS>
__global__ __launch_bounds__(128) void gemm_kernel(
    const float* __restrict__ A, const float* __restrict__ W,
    const float* __restrict__ bias, float* __restrict__ out,
    int relu_flag) {
  __shared__ float As[ROWS * KD];
  const int row0 = blockIdx.x * ROWS;
  const int tid = threadIdx.x;
  for (int i = tid; i < ROWS * KD; i += 128) As[i] = A[(size_t)row0 * KD + i];
  __syncthreads();
  float acc[ROWS];
#pragma unroll
  for (int r = 0; r < ROWS; r++) acc[r] = 0.f;
  for (int k = 0; k < KD; k++) {
    float w = W[k * 128 + tid];
#pragma unroll
    for (int r = 0; r < ROWS; r++) acc[r] += As[r * KD + k] * w;
  }
  float b = bias ? bias[tid] : 0.f;
#pragma unroll
  for (int r = 0; r < ROWS; r++) {
    float v = acc[r] + b;
    if (relu_flag) v = fmaxf(v, 0.f);
    out[(size_t)(row0 + r) * 128 + tid] = v;
  }
}

// ---------------- outer-GAT GEMM: f3[G,128] = xp[G,1024] @ W3[1024,128] ----------------
__global__ __launch_bounds__(256) void gemm1024_kernel(
    const float* __restrict__ A, const float* __restrict__ W,
    float* __restrict__ out) {
  __shared__ float As[8 * 1024];
  __shared__ float red[8][256];
  const int t = threadIdx.x;
  const int row0 = blockIdx.x * 8;
  for (int idx = t; idx < 8 * 256; idx += 256) {
    int r = idx >> 8, c4 = (idx & 255) << 2;
    *(float4*)&As[r * 1024 + c4] = *(const float4*)(A + (size_t)(row0 + r) * 1024 + c4);
  }
  __syncthreads();
  const int col = t & 127, kh = t >> 7;
  const int k0 = kh * 512;
  float acc[8];
#pragma unroll
  for (int r = 0; r < 8; r++) acc[r] = 0.f;
  for (int k = k0; k < k0 + 512; k += 4) {
    float w0 = W[(size_t)(k + 0) * 128 + col];
    float w1 = W[(size_t)(k + 1) * 128 + col];
    float w2 = W[(size_t)(k + 2) * 128 + col];
    float w3 = W[(size_t)(k + 3) * 128 + col];
#pragma unroll
    for (int r = 0; r < 8; r++) {
      float4 a = *(const float4*)&As[r * 1024 + k];
      acc[r] += a.x * w0 + a.y * w1 + a.z * w2 + a.w * w3;
    }
  }
#pragma unroll
  for (int r = 0; r < 8; r++) red[r][t] = acc[r];
  __syncthreads();
  for (int idx = t; idx < 1024; idx += 256) {
    int r = idx >> 7, c = idx & 127;
    out[(size_t)(row0 + r) * 128 + c] = red[r][c] + red[r][128 + c];
  }
}

// ---------------- W pack: fragment-ordered split-bf16 table ----------------
__global__ void pack_w_kernel(const float* __restrict__ W,
                              bfu* __restrict__ hi, bfu* __restrict__ lo) {
  int i = blockIdx.x * 256 + threadIdx.x;  // 0..16383
  if (i >= 16384) return;
  int k = i >> 7, n = i & 127;
  float w = W[i];
  bfu h = f2b(w);
  bfu l = f2b(w - b2f(h));
  int kk = k >> 5, k5 = k & 31, quad = k5 >> 3, j = k5 & 7;
  int tt = n >> 4, m16 = n & 15;
  int pos = ((((kk * 8 + tt) * 4 + quad) * 16) + m16) * 8 + j;
  hi[pos] = h;
  lo[pos] = l;
}

// ---------------- MFMA split-precision GEMM (LDS-free) ----------------
template <int SRC_MODE, int EPI>
__global__ __launch_bounds__(256) void mfma_gemm(
    const float* A, const float* __restrict__ temb,
    const int* __restrict__ hidx,
    const bfu* __restrict__ WfHi, const bfu* __restrict__ WfLo,
    const float* __restrict__ bias, void* out,
    const float* __restrict__ al, const float* __restrict__ ar,
    float* __restrict__ el, float* __restrict__ er,
    float* __restrict__ keyb) {
  const int t = threadIdx.x;
  const int lane = t & 63, wv_ = t >> 6;
  const int m16 = lane & 15, quad = lane >> 4;
  const int rowbase = blockIdx.x * 64 + wv_ * 16;
  const int grow = rowbase + m16;
  const float* arow = (SRC_MODE == 1) ? (temb + (size_t)hidx[grow] * 128)
                                      : (A + (size_t)grow * 128);
  f32x4 acc[8];
#pragma unroll
  for (int i = 0; i < 8; i++) acc[i] = (f32x4){0.f, 0.f, 0.f, 0.f};
#pragma unroll
  for (int kk = 0; kk < 4; kk++) {
    int k0 = kk * 32 + quad * 8;
    float av[8];
    *(float4*)&av[0] = *(const float4*)(arow + k0);
    *(float4*)&av[4] = *(const float4*)(arow + k0 + 4);
    if (SRC_MODE == 1) {
#pragma unroll
      for (int i = 0; i < 8; i++) av[i] = fmaxf(av[i], 0.f);
    }
    bf16x8 ahi, alo;
#pragma unroll
    for (int i = 0; i < 8; i++) {
      bfu hi = f2b(av[i]);
      bfu lo = f2b(av[i] - b2f(hi));
      ahi[i] = (short)hi;
      alo[i] = (short)lo;
    }
#pragma unroll
    for (int tt = 0; tt < 8; tt++) {
      int pos = ((((kk * 8 + tt) * 4 + quad) * 16) + m16) * 8;
      bf16x8 bhi = *(const bf16x8*)&WfHi[pos];
      bf16x8 blo = *(const bf16x8*)&WfLo[pos];
      acc[tt] = __builtin_amdgcn_mfma_f32_16x16x32_bf16(ahi, bhi, acc[tt], 0, 0, 0);
      acc[tt] = __builtin_amdgcn_mfma_f32_16x16x32_bf16(ahi, blo, acc[tt], 0, 0, 0);
      acc[tt] = __builtin_amdgcn_mfma_f32_16x16x32_bf16(alo, bhi, acc[tt], 0, 0, 0);
    }
  }
  if (EPI == 1) {
    float pl[4] = {0.f, 0.f, 0.f, 0.f}, pr[4] = {0.f, 0.f, 0.f, 0.f};
#pragma unroll
    for (int tt = 0; tt < 8; tt++) {
      int col = tt * 16 + m16;
      float alv = al[col], arv = ar[col];
#pragma unroll
      for (int r = 0; r < 4; r++) {
        float v = acc[tt][r];
        ((bfu*)out)[(size_t)(rowbase + quad * 4 + r) * 128 + col] = f2b(v);
        pl[r] += v * alv;
        pr[r] += v * arv;
      }
    }
#pragma unroll
    for (int r = 0; r < 4; r++) {
      float a0 = pl[r], a1 = pr[r];
#pragma unroll
      for (int off = 1; off < 16; off <<= 1) {
        a0 += __shfl_xor(a0, off);
        a1 += __shfl_xor(a1, off);
      }
      if (m16 == 0) {
        el[rowbase + quad * 4 + r] = a0;
        er[rowbase + quad * 4 + r] = a1;
      }
    }
  } else {  // EPI == 2
    float pm[4] = {-INFINITY, -INFINITY, -INFINITY, -INFINITY};
#pragma unroll
    for (int tt = 0; tt < 8; tt++) {
      int col = tt * 16 + m16;
      float bv = bias[col];
#pragma unroll
      for (int r = 0; r < 4; r++) {
        float v = fmaxf(acc[tt][r] + bv, 0.f);
        ((float*)out)[(size_t)(rowbase + quad * 4 + r) * 128 + col] = v;
        pm[r] = fmaxf(pm[r], v);
      }
    }
#pragma unroll
    for (int r = 0; r < 4; r++) {
      float a0 = pm[r];
#pragma unroll
      for (int off = 1; off < 16; off <<= 1) a0 = fmaxf(a0, __shfl_xor(a0, off));
      if (m16 == 0) keyb[rowbase + quad * 4 + r] = a0;
    }
  }
}

// ---------------- attention logits (outer graph, fallback) ----------------
__global__ __launch_bounds__(64) void attn_logits_kernel(
    const float* __restrict__ f, const float* __restrict__ al,
    const float* __restrict__ ar, float* __restrict__ el,
    float* __restrict__ er) {
  int node = blockIdx.x, lane = threadIdx.x;
  float v1 = f[(size_t)node * 128 + lane];
  float v2 = f[(size_t)node * 128 + 64 + lane];
  float sl = v1 * al[lane] + v2 * al[64 + lane];
  float sr = v1 * ar[lane] + v2 * ar[64 + lane];
#pragma unroll
  for (int off = 32; off; off >>= 1) {
    sl += __shfl_down(sl, off);
    sr += __shfl_down(sr, off);
  }
  if (lane == 0) { el[node] = sl; er[node] = sr; }
}

// ---------------- CSR build ----------------
// pass 1: rank[e] = within-row arrival index; cnt accumulates the histogram.
__global__ void hist_rank_kernel(const int* __restrict__ dst, int* __restrict__ cnt,
                                 int* __restrict__ rank, int nE) {
  int e = blockIdx.x * 256 + threadIdx.x;
  if (e < nE) rank[e] = atomicAdd(&cnt[dst[e]], 1);
}

__global__ __launch_bounds__(256) void scan_block_kernel(
    const int* __restrict__ cnt, int* __restrict__ excl, int* __restrict__ part) {
  __shared__ int s[256];
  int blk = blockIdx.x, tid = threadIdx.x;
  int base = blk * 1024 + tid * 4;
  int a0 = cnt[base], a1 = cnt[base + 1], a2 = cnt[base + 2], a3 = cnt[base + 3];
  int tsum = a0 + a1 + a2 + a3;
  s[tid] = tsum; __syncthreads();
  for (int off = 1; off < 256; off <<= 1) {
    int v = (tid >= off) ? s[tid - off] : 0;
    __syncthreads();
    s[tid] += v;
    __syncthreads();
  }
  int texcl = s[tid] - tsum;
  excl[base]     = texcl;
  excl[base + 1] = texcl + a0;
  excl[base + 2] = texcl + a0 + a1;
  excl[base + 3] = texcl + a0 + a1 + a2;
  if (tid == 255) part[blk] = s[255];
}

__global__ __launch_bounds__(128) void scan_part_kernel(int* __restrict__ part) {
  __shared__ int s[128];
  int tid = threadIdx.x;
  int orig = part[tid];
  s[tid] = orig; __syncthreads();
  for (int off = 1; off < 128; off <<= 1) {
    int v = (tid >= off) ? s[tid - off] : 0;
    __syncthreads();
    s[tid] += v;
    __syncthreads();
  }
  part[tid] = s[tid] - orig;
}

__global__ void scan_add_kernel(int* __restrict__ row_ptr, const int* __restrict__ part,
                                int n, int total) {
  int i = blockIdx.x * 256 + threadIdx.x;
  if (i < n) row_ptr[i] += part[i >> 10];
  if (i == 0) row_ptr[n] = total;
}

// pass 2: atomic-free placement (fire-and-forget random write)
__global__ void scatter2_kernel(const int* __restrict__ dst, const int* __restrict__ src,
                                const int* __restrict__ row_ptr, const int* __restrict__ rank,
                                int* __restrict__ adj_src, int nE) {
  int e = blockIdx.x * 256 + threadIdx.x;
  if (e >= nE) return;
  adj_src[row_ptr[dst[e]] + rank[e]] = src[e];
}

// ---------------- fused CSR GAT aggregation: one 64-lane wave per dst ----------------
__global__ __launch_bounds__(256) void gat_aggregate_csr_kernel(
    const bfu* __restrict__ F, const float* __restrict__ el,
    const float* __restrict__ er, const int* __restrict__ row_ptr,
    const int* __restrict__ adj_src,
    const float* __restrict__ bias, float* __restrict__ outX) {
  const int lane = threadIdx.x & 63;
  const int d = blockIdx.x * 4 + (threadIdx.x >> 6);
  const int c0 = lane * 2;
  int beg = row_ptr[d];
  int n = row_ptr[d + 1] - beg;
  float2 bv = *(const float2*)&bias[c0];
  if (n == 0) {
    float2 o; o.x = fmaxf(bv.x, 0.f); o.y = fmaxf(bv.y, 0.f);
    *(float2*)&outX[(size_t)d * 128 + c0] = o;
    return;
  }
  float er_d = er[d];
  float2 acc = make_float2(0.f, 0.f);
  if (n <= 64) {
    int sv = 0; float sc = -INFINITY;
    if (lane < n) {
      sv = adj_src[beg + lane];
      float v = el[sv] + er_d;
      sc = v > 0.f ? v : 0.2f * v;
    }
    float m = sc;
#pragma unroll
    for (int off = 32; off; off >>= 1) m = fmaxf(m, __shfl_xor(m, off));
    float ex = (lane < n) ? expf(sc - m) : 0.f;
    float s = ex;
#pragma unroll
    for (int off = 32; off; off >>= 1) s += __shfl_xor(s, off);
    float wt = ex / s;
    for (int j = 0; j < n; j += 4) {
      int   s0 = __shfl(sv, j);
      float w0 = __shfl(wt, j);
      int   j1 = (j + 1 < n) ? j + 1 : j;
      int   s1 = __shfl(sv, j1); float w1 = (j + 1 < n) ? __shfl(wt, j1) : 0.f;
      int   j2 = (j + 2 < n) ? j + 2 : j;
      int   s2 = __shfl(sv, j2); float w2 = (j + 2 < n) ? __shfl(wt, j2) : 0.f;
      int   j3 = (j + 3 < n) ? j + 3 : j;
      int   s3 = __shfl(sv, j3); float w3 = (j + 3 < n) ? __shfl(wt, j3) : 0.f;
      ushort2 f0 = *(const ushort2*)&F[(size_t)s0 * 128 + c0];
      ushort2 f1 = *(const ushort2*)&F[(size_t)s1 * 128 + c0];
      ushort2 f2 = *(const ushort2*)&F[(size_t)s2 * 128 + c0];
      ushort2 f3 = *(const ushort2*)&F[(size_t)s3 * 128 + c0];
      acc.x += w0 * b2f(f0.x) + w1 * b2f(f1.x) + w2 * b2f(f2.x) + w3 * b2f(f3.x);
      acc.y += w0 * b2f(f0.y) + w1 * b2f(f1.y) + w2 * b2f(f2.y) + w3 * b2f(f3.y);
    }
  } else {
    float lm = -INFINITY;
    for (int t = lane; t < n; t += 64) {
      int sv = adj_src[beg + t];
      float v = el[sv] + er_d;
      v = v > 0.f ? v : 0.2f * v;
      lm = fmaxf(lm, v);
    }
#pragma unroll
    for (int off = 32; off; off >>= 1) lm = fmaxf(lm, __shfl_xor(lm, off));
    float ls = 0.f;
    for (int t = lane; t < n; t += 64) {
      int sv = adj_src[beg + t];
      float v = el[sv] + er_d;
      v = v > 0.f ? v : 0.2f * v;
      ls += expf(v - lm);
    }
#pragma unroll
    for (int off = 32; off; off >>= 1) ls += __shfl_xor(ls, off);
    for (int base = 0; base < n; base += 64) {
      int t = base + lane;
      int sv = 0; float wt = 0.f;
      if (t < n) {
        sv = adj_src[beg + t];
        float v = el[sv] + er_d;
        v = v > 0.f ? v : 0.2f * v;
        wt = expf(v - lm) / ls;
      }
      int cnt = min(64, n - base);
      for (int j = 0; j < cnt; ++j) {
        int s0 = __shfl(sv, j);
        float w0 = __shfl(wt, j);
        ushort2 f0 = *(const ushort2*)&F[(size_t)s0 * 128 + c0];
        acc.x += w0 * b2f(f0.x);
        acc.y += w0 * b2f(f0.y);
      }
    }
  }
  float2 o;
  o.x = fmaxf(acc.x + bv.x, 0.f);
  o.y = fmaxf(acc.y + bv.y, 0.f);
  *(float2*)&outX[(size_t)d * 128 + c0] = o;
}

// ---------------- atomic-path edge kernels (outer graph + fallback) ----------------
static __device__ __forceinline__ void atomicMaxF(float* addr, float v) {
  int iv = __float_as_int(v);
  if (iv >= 0) atomicMax((int*)addr, iv);
  else atomicMin((unsigned int*)addr, (unsigned int)iv);
}

static __device__ __forceinline__ float edge_score(const float* el, const float* er,
                                                   int sv, int dv) {
  float v = el[sv] + er[dv];
  return v > 0.f ? v : 0.2f * v;
}

__global__ void edge_max_kernel(const float* __restrict__ el,
                                const float* __restrict__ er,
                                const int* __restrict__ src,
                                const int* __restrict__ dst,
                                float* __restrict__ m, int nE) {
  int e = blockIdx.x * 256 + threadIdx.x;
  if (e >= nE) return;
  atomicMaxF(&m[dst[e]], edge_score(el, er, src[e], dst[e]));
}

__global__ void edge_expsum_kernel(const float* __restrict__ el,
                                   const float* __restrict__ er,
                                   const float* __restrict__ m,
                                   const int* __restrict__ src,
                                   const int* __restrict__ dst,
                                   float* __restrict__ s, int nE) {
  int e = blockIdx.x * 256 + threadIdx.x;
  if (e >= nE) return;
  int d = dst[e];
  atomicAdd(&s[d], expf(edge_score(el, er, src[e], d) - m[d]));
}

__global__ __launch_bounds__(128) void edge_aggregate_kernel(
    const float* __restrict__ f, const float* __restrict__ el,
    const float* __restrict__ er, const float* __restrict__ m,
    const float* __restrict__ s, const int* __restrict__ src,
    const int* __restrict__ dst, float* __restrict__ out, int nE) {
  int e = blockIdx.x;
  int d = threadIdx.x;
  int sv = src[e], dv = dst[e];
  float alpha = expf(edge_score(el, er, sv, dv) - m[dv]) / s[dv];
  atomicAdd(&out[(size_t)dv * 128 + d], alpha * f[(size_t)sv * 128 + d]);
}

__global__ void bias_relu_kernel(float* __restrict__ x,
                                 const float* __restrict__ b, int total) {
  int i = blockIdx.x * 256 + threadIdx.x;
  if (i >= total) return;
  x[i] = fmaxf(x[i] + b[i & 127], 0.f);
}

// ---------------- sort pooling ----------------
__global__ __launch_bounds__(64) void row_max_kernel(const float* __restrict__ x,
                                                     float* __restrict__ key) {
  int node = blockIdx.x, lane = threadIdx.x;
  float v = fmaxf(x[(size_t)node * 128 + lane], x[(size_t)node * 128 + 64 + lane]);
#pragma unroll
  for (int off = 32; off; off >>= 1) v = fmaxf(v, __shfl_down(v, off));
  if (lane == 0) key[node] = v;
}

__global__ __launch_bounds__(64) void select_topk_kernel(
    const float* __restrict__ key, int* __restrict__ sel) {
  __shared__ float keys[NPG];
  int g = blockIdx.x, t = threadIdx.x;
  keys[t] = key[(size_t)g * NPG + t];
  __syncthreads();
  float myk = keys[t];
  int rank = 0;
  for (int j = 0; j < NPG; ++j) {
    float kj = keys[j];
    rank += (kj > myk) || (kj == myk && j < t);
  }
  if (rank < KK) sel[g * KK + rank] = t;
}

__global__ __launch_bounds__(128) void sort_rows_kernel(
    const float* __restrict__ x, const int* __restrict__ sel,
    float* __restrict__ xp) {
  __shared__ float v[128];
  int b = blockIdx.x;
  int t = threadIdx.x;
  int g = b >> 3, r = b & 7;
  int node = sel[b];
  v[t] = x[(size_t)(g * NPG + node) * 128 + t];
  __syncthreads();
  for (int k = 2; k <= 128; k <<= 1) {
    for (int j = k >> 1; j > 0; j >>= 1) {
      int ixj = t ^ j;
      if (ixj > t) {
        float a = v[t], bb = v[ixj];
        bool asc = ((t & k) == 0);
        if (asc ? (a > bb) : (a < bb)) { v[t] = bb; v[ixj] = a; }
      }
      __syncthreads();
    }
  }
  xp[(size_t)g * (KK * 128) + r * 128 + t] = v[t];
}

// ---------------- classifier ----------------
__global__ __launch_bounds__(64) void classifier_kernel(
    const float* __restrict__ x, const float* __restrict__ Wc,
    const float* __restrict__ bc, float* __restrict__ out) {
  int g = blockIdx.x, lane = threadIdx.x;
  float v1 = x[(size_t)g * 128 + lane];
  float v2 = x[(size_t)g * 128 + 64 + lane];
  float a0 = v1 * Wc[lane * 2 + 0] + v2 * Wc[(64 + lane) * 2 + 0];
  float a1 = v1 * Wc[lane * 2 + 1] + v2 * Wc[(64 + lane) * 2 + 1];
#pragma unroll
  for (int off = 32; off; off >>= 1) {
    a0 += __shfl_down(a0, off);
    a1 += __shfl_down(a1, off);
  }
  if (lane == 0) {
    out[g * 2 + 0] = a0 + bc[0];
    out[g * 2 + 1] = a1 + bc[1];
  }
}

// ---------------- launcher ----------------
extern "C" void kernel_launch(void* const* d_in, const int* in_sizes, int n_in,
                              void* d_out, int out_size, void* d_ws, size_t ws_size,
                              hipStream_t stream) {
  const size_t BASE_FLOATS = (size_t)NN * DD * 2 + (size_t)NN * 4;  // X,F,el,er,mx,sm
  const size_t CSR_INTS = (size_t)(NN + 1) + NN + EE + 128;          // row_ptr,cursor,adj,part
  if (ws_size < BASE_FLOATS * sizeof(float)) {
    hipMemsetAsync(d_out, 0, (size_t)out_size * sizeof(float), stream);
    return;
  }
  const bool use_csr = ws_size >= BASE_FLOATS * sizeof(float) + CSR_INTS * sizeof(int);

  const int* h      = (const int*)d_in[0];
  const int* g_src  = (const int*)d_in[1];
  const int* g_dst  = (const int*)d_in[2];
  const int* fg_src = (const int*)d_in[3];
  const int* fg_dst = (const int*)d_in[4];
  const float* temb = (const float*)d_in[5];
  const float* W1 = (const float*)d_in[6];
  const float* al1 = (const float*)d_in[7];
  const float* ar1 = (const float*)d_in[8];
  const float* b1 = (const float*)d_in[9];
  const float* W2 = (const float*)d_in[10];
  const float* al2 = (const float*)d_in[11];
  const float* ar2 = (const float*)d_in[12];
  const float* b2 = (const float*)d_in[13];
  const float* W3 = (const float*)d_in[14];
  const float* al3 = (const float*)d_in[15];
  const float* ar3 = (const float*)d_in[16];
  const float* b3 = (const float*)d_in[17];
  const float* Wf = (const float*)d_in[18];
  const float* bfv = (const float*)d_in[19];
  const float* Wl = (const float*)d_in[20];
  const float* bl = (const float*)d_in[21];
  const float* Wl1 = (const float*)d_in[22];
  const float* bl1 = (const float*)d_in[23];
  const float* Wc = (const float*)d_in[24];
  const float* bc = (const float*)d_in[25];
  float* out = (float*)d_out;

  // ---- workspace layout ----
  float* ws = (float*)d_ws;
  float* X  = ws;
  float* F  = X + (size_t)NN * DD;   // used as bf16 (first half) on CSR path
  float* el = F + (size_t)NN * DD;
  float* er = el + NN;
  float* mx = er + NN;
  float* sm = mx + NN;
  int* row_ptr = (int*)(sm + NN);
  int* cursor  = row_ptr + NN + 1;
  int* adj_src = cursor + NN;
  int* part    = adj_src + EE;
  // rank buffer aliases X (X is first written after CSR build completes):
  int* rankb = (int*)X;              // EE ints = 4 MB << 64 MB X region
  // packed W tables live in mx/sm (unused by CSR-path inner layers):
  bfu* w1h = (bfu*)mx;            // 16384 each
  bfu* w1l = w1h + 16384;
  bfu* w2h = w1l + 16384;
  bfu* w2l = w2h + 16384;
  bfu* wfh = w2l + 16384;
  bfu* wfl = wfh + 16384;          // total 192KB < 512KB (mx region alone)
  // carved from F once F is dead (after layer-2 aggregation):
  float* xp   = F;
  float* f3   = F + 2097152;
  float* g3   = f3 + (size_t)GG * DD;
  float* t1   = g3 + (size_t)GG * DD;
  float* t2   = t1 + (size_t)GG * DD;
  float* keyb = t2 + (size_t)GG * DD;
  int*   sel  = (int*)(keyb + NN);

  const int totalND = NN * DD;

  if (use_csr) {
    bfu* Fb = (bfu*)F;
    // ---- build CSR of inner graph by dst (reused by both GAT layers) ----
    zero_int_kernel<<<NN / 256, 256, 0, stream>>>(cursor, NN);
    hist_rank_kernel<<<EE / 256, 256, 0, stream>>>(g_dst, cursor, rankb, EE);
    scan_block_kernel<<<NN / 1024, 256, 0, stream>>>(cursor, row_ptr, part);
    scan_part_kernel<<<1, 128, 0, stream>>>(part);
    scan_add_kernel<<<(NN + 255) / 256, 256, 0, stream>>>(row_ptr, part, NN, EE);
    scatter2_kernel<<<EE / 256, 256, 0, stream>>>(g_dst, g_src, row_ptr, rankb, adj_src, EE);

    // pack the three 128x128 weights into fragment-ordered split tables
    pack_w_kernel<<<64, 256, 0, stream>>>(W1, w1h, w1l);
    pack_w_kernel<<<64, 256, 0, stream>>>(W2, w2h, w2l);
    pack_w_kernel<<<64, 256, 0, stream>>>(Wf, wfh, wfl);

    // layer 1: F(bf16) = relu(temb[h]) @ W1 (MFMA split) + el/er epilogue
    mfma_gemm<1, 1><<<NN / 64, 256, 0, stream>>>(
        nullptr, temb, h, w1h, w1l, nullptr, Fb, al1, ar1, el, er, nullptr);
    gat_aggregate_csr_kernel<<<NN / 4, 256, 0, stream>>>(Fb, el, er, row_ptr, adj_src, b1, X);

    // layer 2
    mfma_gemm<0, 1><<<NN / 64, 256, 0, stream>>>(
        X, nullptr, nullptr, w2h, w2l, nullptr, Fb, al2, ar2, el, er, nullptr);
    gat_aggregate_csr_kernel<<<NN / 4, 256, 0, stream>>>(Fb, el, er, row_ptr, adj_src, b2, X);

    // linear_forward in-place + fused row-max
    mfma_gemm<0, 2><<<NN / 64, 256, 0, stream>>>(
        X, nullptr, nullptr, wfh, wfl, bfv, X, nullptr, nullptr, nullptr, nullptr, keyb);
  } else {
    embed_relu_kernel<<<totalND / 256, 256, 0, stream>>>(temb, h, X, totalND);
    auto gat_inner = [&](const float* W, const float* al, const float* ar, const float* bb) {
      gemm_kernel<DD, 8><<<NN / 8, 128, 0, stream>>>(X, W, nullptr, F, 0);
      attn_logits_kernel<<<NN, 64, 0, stream>>>(F, al, ar, el, er);
      init_softmax_kernel<<<(NN + 255) / 256, 256, 0, stream>>>(mx, sm, NN);
      fill_f32_kernel<<<totalND / 256, 256, 0, stream>>>(X, 0.f, totalND);
      edge_max_kernel<<<(EE + 255) / 256, 256, 0, stream>>>(el, er, g_src, g_dst, mx, EE);
      edge_expsum_kernel<<<(EE + 255) / 256, 256, 0, stream>>>(el, er, mx, g_src, g_dst, sm, EE);
      edge_aggregate_kernel<<<EE, 128, 0, stream>>>(F, el, er, mx, sm, g_src, g_dst, X, EE);
      bias_relu_kernel<<<totalND / 256, 256, 0, stream>>>(X, bb, totalND);
    };
    gat_inner(W1, al1, ar1, b1);
    gat_inner(W2, al2, ar2, b2);
    gemm_kernel<DD, 8><<<NN / 8, 128, 0, stream>>>(X, Wf, bfv, X, 1);
    row_max_kernel<<<NN, 64, 0, stream>>>(X, keyb);
  }

  // sort pooling -> xp [G, 1024]
  select_topk_kernel<<<GG, 64, 0, stream>>>(keyb, sel);
  sort_rows_kernel<<<GG * KK, 128, 0, stream>>>(X, sel, xp);

  // outer GAT over fg (atomic path — small)
  gemm1024_kernel<<<GG / 8, 256, 0, stream>>>(xp, W3, f3);
  attn_logits_kernel<<<GG, 64, 0, stream>>>(f3, al3, ar3, el, er);
  init_softmax_kernel<<<(GG + 255) / 256, 256, 0, stream>>>(mx, sm, GG);
  fill_f32_kernel<<<(GG * DD + 255) / 256, 256, 0, stream>>>(g3, 0.f, GG * DD);
  edge_max_kernel<<<(EFN + 255) / 256, 256, 0, stream>>>(el, er, fg_src, fg_dst, mx, EFN);
  edge_expsum_kernel<<<(EFN + 255) / 256, 256, 0, stream>>>(el, er, mx, fg_src, fg_dst, sm, EFN);
  edge_aggregate_kernel<<<EFN, 128, 0, stream>>>(f3, el, er, mx, sm, fg_src, fg_dst, g3, EFN);
  bias_relu_kernel<<<(GG * DD + 255) / 256, 256, 0, stream>>>(g3, b3, GG * DD);

  // t1 = relu(g3 @ Wl + bl); t2 = relu(t1 @ Wl1 + bl1)
  gemm_kernel<DD, 8><<<GG / 8, 128, 0, stream>>>(g3, Wl, bl, t1, 1);
  gemm_kernel<DD, 8><<<GG / 8, 128, 0, stream>>>(t1, Wl1, bl1, t2, 1);

  // classifier -> fp32 out [G,2]
  classifier_kernel<<<GG, 64, 0, stream>>>(t2, Wc, bc, out);
}

// Round 17
// 479.099 us; speedup vs baseline: 1.4277x; 1.1002x over previous
//
#include <hip/hip_runtime.h>
#include <math.h>

#define NN   131072   // total inner nodes
#define GG   2048     // graphs
#define NPG  64       // nodes per graph
#define EE   1048576  // inner edges
#define EFN  32768    // outer edges
#define DD   128      // feature dim
#define KK   8        // sortpool k

typedef unsigned short bfu;  // raw bf16 bits
typedef short bf16x8 __attribute__((ext_vector_type(8)));
typedef float f32x4 __attribute__((ext_vector_type(4)));

static __device__ __forceinline__ bfu f2b(float f) {  // RNE f32 -> bf16
  unsigned u = __float_as_uint(f);
  u += 0x7FFFu + ((u >> 16) & 1u);
  return (bfu)(u >> 16);
}
static __device__ __forceinline__ float b2f(bfu b) {
  return __uint_as_float(((unsigned)b) << 16);
}

// ---------------- utility ----------------
__global__ void fill_f32_kernel(float* __restrict__ p, float v, int nElems) {
  int i = blockIdx.x * 256 + threadIdx.x;
  if (i < nElems) p[i] = v;
}

__global__ void zero_int_kernel(int* __restrict__ p, int nElems) {
  int i = blockIdx.x * 256 + threadIdx.x;
  if (i < nElems) p[i] = 0;
}

__global__ void init_softmax_kernel(float* __restrict__ mx, float* __restrict__ sm, int nElems) {
  int i = blockIdx.x * 256 + threadIdx.x;
  if (i < nElems) { mx[i] = -INFINITY; sm[i] = 0.f; }
}

// x[i] = relu(token_emb[h[node]][d])   (fallback path only)
__global__ void embed_relu_kernel(const float* __restrict__ temb,
                                  const int* __restrict__ h,
                                  float* __restrict__ x, int total) {
  int i = blockIdx.x * 256 + threadIdx.x;
  if (i >= total) return;
  int node = i >> 7, d = i & 127;
  x[i] = fmaxf(temb[h[node] * DD + d], 0.f);
}

// ---------------- small / generic GEMM (outer graph, fallback) ----------------
template <int KD, int ROWS>
__global__ __launch_bounds__(128) void gemm_kernel(
    const float* __restrict__ A, const float* __restrict__ W,
    const float* __restrict__ bias, float* __restrict__ out,
    int relu_flag) {
  __shared__ float As[ROWS * KD];
  const int row0 = blockIdx.x * ROWS;
  const int tid = threadIdx.x;
  for (int i = tid; i < ROWS * KD; i += 128) As[i] = A[(size_t)row0 * KD + i];
  __syncthreads();
  float acc[ROWS];
#pragma unroll
  for (int r = 0; r < ROWS; r++) acc[r] = 0.f;
  for (int k = 0; k < KD; k++) {
    float w = W[k * 128 + tid];
#pragma unroll
    for (int r = 0; r < ROWS; r++) acc[r] += As[r * KD + k] * w;
  }
  float b = bias ? bias[tid] : 0.f;
#pragma unroll
  for (int r = 0; r < ROWS; r++) {
    float v = acc[r] + b;
    if (relu_flag) v = fmaxf(v, 0.f);
    out[(size_t)(row0 + r) * 128 + tid] = v;
  }
}

// ---------------- outer-GAT GEMM: f3[G,128] = xp[G,1024] @ W3[1024,128] ----------------
__global__ __launch_bounds__(256) void gemm1024_kernel(
    const float* __restrict__ A, const float* __restrict__ W,
    float* __restrict__ out) {
  __shared__ float As[8 * 1024];
  __shared__ float red[8][256];
  const int t = threadIdx.x;
  const int row0 = blockIdx.x * 8;
  for (int idx = t; idx < 8 * 256; idx += 256) {
    int r = idx >> 8, c4 = (idx & 255) << 2;
    *(float4*)&As[r * 1024 + c4] = *(const float4*)(A + (size_t)(row0 + r) * 1024 + c4);
  }
  __syncthreads();
  const int col = t & 127, kh = t >> 7;
  const int k0 = kh * 512;
  float acc[8];
#pragma unroll
  for (int r = 0; r < 8; r++) acc[r] = 0.f;
  for (int k = k0; k < k0 + 512; k += 4) {
    float w0 = W[(size_t)(k + 0) * 128 + col];
    float w1 = W[(size_t)(k + 1) * 128 + col];
    float w2 = W[(size_t)(k + 2) * 128 + col];
    float w3 = W[(size_t)(k + 3) * 128 + col];
#pragma unroll
    for (int r = 0; r < 8; r++) {
      float4 a = *(const float4*)&As[r * 1024 + k];
      acc[r] += a.x * w0 + a.y * w1 + a.z * w2 + a.w * w3;
    }
  }
#pragma unroll
  for (int r = 0; r < 8; r++) red[r][t] = acc[r];
  __syncthreads();
  for (int idx = t; idx < 1024; idx += 256) {
    int r = idx >> 7, c = idx & 127;
    out[(size_t)(row0 + r) * 128 + c] = red[r][c] + red[r][128 + c];
  }
}

// ---------------- W pack: fragment-ordered split-bf16 table ----------------
__global__ void pack_w_kernel(const float* __restrict__ W,
                              bfu* __restrict__ hi, bfu* __restrict__ lo) {
  int i = blockIdx.x * 256 + threadIdx.x;  // 0..16383
  if (i >= 16384) return;
  int k = i >> 7, n = i & 127;
  float w = W[i];
  bfu h = f2b(w);
  bfu l = f2b(w - b2f(h));
  int kk = k >> 5, k5 = k & 31, quad = k5 >> 3, j = k5 & 7;
  int tt = n >> 4, m16 = n & 15;
  int pos = ((((kk * 8 + tt) * 4 + quad) * 16) + m16) * 8 + j;
  hi[pos] = h;
  lo[pos] = l;
}

// ---------------- MFMA split-precision GEMM (LDS-free) ----------------
template <int SRC_MODE, int EPI>
__global__ __launch_bounds__(256) void mfma_gemm(
    const float* A, const float* __restrict__ temb,
    const int* __restrict__ hidx,
    const bfu* __restrict__ WfHi, const bfu* __restrict__ WfLo,
    const float* __restrict__ bias, void* out,
    const float* __restrict__ al, const float* __restrict__ ar,
    float* __restrict__ el, float* __restrict__ er,
    float* __restrict__ keyb) {
  const int t = threadIdx.x;
  const int lane = t & 63, wv_ = t >> 6;
  const int m16 = lane & 15, quad = lane >> 4;
  const int rowbase = blockIdx.x * 64 + wv_ * 16;
  const int grow = rowbase + m16;
  const float* arow = (SRC_MODE == 1) ? (temb + (size_t)hidx[grow] * 128)
                                      : (A + (size_t)grow * 128);
  f32x4 acc[8];
#pragma unroll
  for (int i = 0; i < 8; i++) acc[i] = (f32x4){0.f, 0.f, 0.f, 0.f};
#pragma unroll
  for (int kk = 0; kk < 4; kk++) {
    int k0 = kk * 32 + quad * 8;
    float av[8];
    *(float4*)&av[0] = *(const float4*)(arow + k0);
    *(float4*)&av[4] = *(const float4*)(arow + k0 + 4);
    if (SRC_MODE == 1) {
#pragma unroll
      for (int i = 0; i < 8; i++) av[i] = fmaxf(av[i], 0.f);
    }
    bf16x8 ahi, alo;
#pragma unroll
    for (int i = 0; i < 8; i++) {
      bfu hi = f2b(av[i]);
      bfu lo = f2b(av[i] - b2f(hi));
      ahi[i] = (short)hi;
      alo[i] = (short)lo;
    }
#pragma unroll
    for (int tt = 0; tt < 8; tt++) {
      int pos = ((((kk * 8 + tt) * 4 + quad) * 16) + m16) * 8;
      bf16x8 bhi = *(const bf16x8*)&WfHi[pos];
      bf16x8 blo = *(const bf16x8*)&WfLo[pos];
      acc[tt] = __builtin_amdgcn_mfma_f32_16x16x32_bf16(ahi, bhi, acc[tt], 0, 0, 0);
      acc[tt] = __builtin_amdgcn_mfma_f32_16x16x32_bf16(ahi, blo, acc[tt], 0, 0, 0);
      acc[tt] = __builtin_amdgcn_mfma_f32_16x16x32_bf16(alo, bhi, acc[tt], 0, 0, 0);
    }
  }
  if (EPI == 1) {
    float pl[4] = {0.f, 0.f, 0.f, 0.f}, pr[4] = {0.f, 0.f, 0.f, 0.f};
#pragma unroll
    for (int tt = 0; tt < 8; tt++) {
      int col = tt * 16 + m16;
      float alv = al[col], arv = ar[col];
#pragma unroll
      for (int r = 0; r < 4; r++) {
        float v = acc[tt][r];
        ((bfu*)out)[(size_t)(rowbase + quad * 4 + r) * 128 + col] = f2b(v);
        pl[r] += v * alv;
        pr[r] += v * arv;
      }
    }
#pragma unroll
    for (int r = 0; r < 4; r++) {
      float a0 = pl[r], a1 = pr[r];
#pragma unroll
      for (int off = 1; off < 16; off <<= 1) {
        a0 += __shfl_xor(a0, off);
        a1 += __shfl_xor(a1, off);
      }
      if (m16 == 0) {
        el[rowbase + quad * 4 + r] = a0;
        er[rowbase + quad * 4 + r] = a1;
      }
    }
  } else {  // EPI == 2
    float pm[4] = {-INFINITY, -INFINITY, -INFINITY, -INFINITY};
#pragma unroll
    for (int tt = 0; tt < 8; tt++) {
      int col = tt * 16 + m16;
      float bv = bias[col];
#pragma unroll
      for (int r = 0; r < 4; r++) {
        float v = fmaxf(acc[tt][r] + bv, 0.f);
        ((float*)out)[(size_t)(rowbase + quad * 4 + r) * 128 + col] = v;
        pm[r] = fmaxf(pm[r], v);
      }
    }
#pragma unroll
    for (int r = 0; r < 4; r++) {
      float a0 = pm[r];
#pragma unroll
      for (int off = 1; off < 16; off <<= 1) a0 = fmaxf(a0, __shfl_xor(a0, off));
      if (m16 == 0) keyb[rowbase + quad * 4 + r] = a0;
    }
  }
}

// ---------------- attention logits (outer graph, fallback) ----------------
__global__ __launch_bounds__(64) void attn_logits_kernel(
    const float* __restrict__ f, const float* __restrict__ al,
    const float* __restrict__ ar, float* __restrict__ el,
    float* __restrict__ er) {
  int node = blockIdx.x, lane = threadIdx.x;
  float v1 = f[(size_t)node * 128 + lane];
  float v2 = f[(size_t)node * 128 + 64 + lane];
  float sl = v1 * al[lane] + v2 * al[64 + lane];
  float sr = v1 * ar[lane] + v2 * ar[64 + lane];
#pragma unroll
  for (int off = 32; off; off >>= 1) {
    sl += __shfl_down(sl, off);
    sr += __shfl_down(sr, off);
  }
  if (lane == 0) { el[node] = sl; er[node] = sr; }
}

// ---------------- CSR build ----------------
__global__ void hist_rank_kernel(const int* __restrict__ dst, int* __restrict__ cnt,
                                 int* __restrict__ rank, int nE) {
  int e = blockIdx.x * 256 + threadIdx.x;
  if (e < nE) rank[e] = atomicAdd(&cnt[dst[e]], 1);
}

__global__ __launch_bounds__(256) void scan_block_kernel(
    const int* __restrict__ cnt, int* __restrict__ excl, int* __restrict__ part) {
  __shared__ int s[256];
  int blk = blockIdx.x, tid = threadIdx.x;
  int base = blk * 1024 + tid * 4;
  int a0 = cnt[base], a1 = cnt[base + 1], a2 = cnt[base + 2], a3 = cnt[base + 3];
  int tsum = a0 + a1 + a2 + a3;
  s[tid] = tsum; __syncthreads();
  for (int off = 1; off < 256; off <<= 1) {
    int v = (tid >= off) ? s[tid - off] : 0;
    __syncthreads();
    s[tid] += v;
    __syncthreads();
  }
  int texcl = s[tid] - tsum;
  excl[base]     = texcl;
  excl[base + 1] = texcl + a0;
  excl[base + 2] = texcl + a0 + a1;
  excl[base + 3] = texcl + a0 + a1 + a2;
  if (tid == 255) part[blk] = s[255];
}

__global__ __launch_bounds__(128) void scan_part_kernel(int* __restrict__ part) {
  __shared__ int s[128];
  int tid = threadIdx.x;
  int orig = part[tid];
  s[tid] = orig; __syncthreads();
  for (int off = 1; off < 128; off <<= 1) {
    int v = (tid >= off) ? s[tid - off] : 0;
    __syncthreads();
    s[tid] += v;
    __syncthreads();
  }
  part[tid] = s[tid] - orig;
}

__global__ void scan_add_kernel(int* __restrict__ row_ptr, const int* __restrict__ part,
                                int n, int total) {
  int i = blockIdx.x * 256 + threadIdx.x;
  if (i < n) row_ptr[i] += part[i >> 10];
  if (i == 0) row_ptr[n] = total;
}

__global__ void scatter2_kernel(const int* __restrict__ dst, const int* __restrict__ src,
                                const int* __restrict__ row_ptr, const int* __restrict__ rank,
                                int* __restrict__ adj_src, int nE) {
  int e = blockIdx.x * 256 + threadIdx.x;
  if (e >= nE) return;
  adj_src[row_ptr[dst[e]] + rank[e]] = src[e];
}

// ---------------- fused CSR GAT aggregation: 32-lane group per dst ----------------
// 8 dst/block (256 thr). Lane owns 4 cols (ushort4 8B gather); softmax via
// 5-round shuffle reduce within the 32-lane group; broadcasts via __shfl from
// the group's base lane.
__global__ __launch_bounds__(256) void gat_aggregate_csr_kernel(
    const bfu* __restrict__ F, const float* __restrict__ el,
    const float* __restrict__ er, const int* __restrict__ row_ptr,
    const int* __restrict__ adj_src,
    const float* __restrict__ bias, float* __restrict__ outX) {
  const int t = threadIdx.x;
  const int l = t & 31;                    // lane in 32-group
  const int gb = t & 32;                   // group base within the wave (0|32)
  const int d = blockIdx.x * 8 + (t >> 5); // dst node
  const int c0 = l * 4;
  int beg = row_ptr[d];
  int n = row_ptr[d + 1] - beg;
  float4 bv = *(const float4*)&bias[c0];
  if (n == 0) {
    float4 o;
    o.x = fmaxf(bv.x, 0.f); o.y = fmaxf(bv.y, 0.f);
    o.z = fmaxf(bv.z, 0.f); o.w = fmaxf(bv.w, 0.f);
    *(float4*)&outX[(size_t)d * 128 + c0] = o;
    return;
  }
  float er_d = er[d];
  float4 acc = make_float4(0.f, 0.f, 0.f, 0.f);
  if (n <= 32) {  // fast path: avg degree 8
    int sv = 0; float sc = -INFINITY;
    if (l < n) {
      sv = adj_src[beg + l];
      float v = el[sv] + er_d;
      sc = v > 0.f ? v : 0.2f * v;
    }
    float m = sc;
#pragma unroll
    for (int off = 16; off; off >>= 1) m = fmaxf(m, __shfl_xor(m, off));
    float ex = (l < n) ? expf(sc - m) : 0.f;
    float s = ex;
#pragma unroll
    for (int off = 16; off; off >>= 1) s += __shfl_xor(s, off);
    float wt = ex / s;
    for (int j = 0; j < n; j += 4) {
      int   s0 = __shfl(sv, gb + j);
      float w0 = __shfl(wt, gb + j);
      int   j1 = (j + 1 < n) ? j + 1 : j;
      int   s1 = __shfl(sv, gb + j1); float w1 = (j + 1 < n) ? __shfl(wt, gb + j1) : 0.f;
      int   j2 = (j + 2 < n) ? j + 2 : j;
      int   s2 = __shfl(sv, gb + j2); float w2 = (j + 2 < n) ? __shfl(wt, gb + j2) : 0.f;
      int   j3 = (j + 3 < n) ? j + 3 : j;
      int   s3 = __shfl(sv, gb + j3); float w3 = (j + 3 < n) ? __shfl(wt, gb + j3) : 0.f;
      ushort4 f0 = *(const ushort4*)&F[(size_t)s0 * 128 + c0];
      ushort4 f1 = *(const ushort4*)&F[(size_t)s1 * 128 + c0];
      ushort4 f2 = *(const ushort4*)&F[(size_t)s2 * 128 + c0];
      ushort4 f3 = *(const ushort4*)&F[(size_t)s3 * 128 + c0];
      acc.x += w0 * b2f(f0.x) + w1 * b2f(f1.x) + w2 * b2f(f2.x) + w3 * b2f(f3.x);
      acc.y += w0 * b2f(f0.y) + w1 * b2f(f1.y) + w2 * b2f(f2.y) + w3 * b2f(f3.y);
      acc.z += w0 * b2f(f0.z) + w1 * b2f(f1.z) + w2 * b2f(f2.z) + w3 * b2f(f3.z);
      acc.w += w0 * b2f(f0.w) + w1 * b2f(f1.w) + w2 * b2f(f2.w) + w3 * b2f(f3.w);
    }
  } else {  // chunked group path (degree > 32 — rare)
    float lm = -INFINITY;
    for (int e = l; e < n; e += 32) {
      int sv = adj_src[beg + e];
      float v = el[sv] + er_d;
      v = v > 0.f ? v : 0.2f * v;
      lm = fmaxf(lm, v);
    }
#pragma unroll
    for (int off = 16; off; off >>= 1) lm = fmaxf(lm, __shfl_xor(lm, off));
    float ls = 0.f;
    for (int e = l; e < n; e += 32) {
      int sv = adj_src[beg + e];
      float v = el[sv] + er_d;
      v = v > 0.f ? v : 0.2f * v;
      ls += expf(v - lm);
    }
#pragma unroll
    for (int off = 16; off; off >>= 1) ls += __shfl_xor(ls, off);
    for (int base = 0; base < n; base += 32) {
      int e = base + l;
      int sv = 0; float wt = 0.f;
      if (e < n) {
        sv = adj_src[beg + e];
        float v = el[sv] + er_d;
        v = v > 0.f ? v : 0.2f * v;
        wt = expf(v - lm) / ls;
      }
      int cnt = min(32, n - base);
      for (int j = 0; j < cnt; ++j) {
        int s0 = __shfl(sv, gb + j);
        float w0 = __shfl(wt, gb + j);
        ushort4 f0 = *(const ushort4*)&F[(size_t)s0 * 128 + c0];
        acc.x += w0 * b2f(f0.x);
        acc.y += w0 * b2f(f0.y);
        acc.z += w0 * b2f(f0.z);
        acc.w += w0 * b2f(f0.w);
      }
    }
  }
  float4 o;
  o.x = fmaxf(acc.x + bv.x, 0.f);
  o.y = fmaxf(acc.y + bv.y, 0.f);
  o.z = fmaxf(acc.z + bv.z, 0.f);
  o.w = fmaxf(acc.w + bv.w, 0.f);
  *(float4*)&outX[(size_t)d * 128 + c0] = o;
}

// ---------------- atomic-path edge kernels (outer graph + fallback) ----------------
static __device__ __forceinline__ void atomicMaxF(float* addr, float v) {
  int iv = __float_as_int(v);
  if (iv >= 0) atomicMax((int*)addr, iv);
  else atomicMin((unsigned int*)addr, (unsigned int)iv);
}

static __device__ __forceinline__ float edge_score(const float* el, const float* er,
                                                   int sv, int dv) {
  float v = el[sv] + er[dv];
  return v > 0.f ? v : 0.2f * v;
}

__global__ void edge_max_kernel(const float* __restrict__ el,
                                const float* __restrict__ er,
                                const int* __restrict__ src,
                                const int* __restrict__ dst,
                                float* __restrict__ m, int nE) {
  int e = blockIdx.x * 256 + threadIdx.x;
  if (e >= nE) return;
  atomicMaxF(&m[dst[e]], edge_score(el, er, src[e], dst[e]));
}

__global__ void edge_expsum_kernel(const float* __restrict__ el,
                                   const float* __restrict__ er,
                                   const float* __restrict__ m,
                                   const int* __restrict__ src,
                                   const int* __restrict__ dst,
                                   float* __restrict__ s, int nE) {
  int e = blockIdx.x * 256 + threadIdx.x;
  if (e >= nE) return;
  int d = dst[e];
  atomicAdd(&s[d], expf(edge_score(el, er, src[e], d) - m[d]));
}

__global__ __launch_bounds__(128) void edge_aggregate_kernel(
    const float* __restrict__ f, const float* __restrict__ el,
    const float* __restrict__ er, const float* __restrict__ m,
    const float* __restrict__ s, const int* __restrict__ src,
    const int* __restrict__ dst, float* __restrict__ out, int nE) {
  int e = blockIdx.x;
  int d = threadIdx.x;
  int sv = src[e], dv = dst[e];
  float alpha = expf(edge_score(el, er, sv, dv) - m[dv]) / s[dv];
  atomicAdd(&out[(size_t)dv * 128 + d], alpha * f[(size_t)sv * 128 + d]);
}

__global__ void bias_relu_kernel(float* __restrict__ x,
                                 const float* __restrict__ b, int total) {
  int i = blockIdx.x * 256 + threadIdx.x;
  if (i >= total) return;
  x[i] = fmaxf(x[i] + b[i & 127], 0.f);
}

// ---------------- sort pooling ----------------
__global__ __launch_bounds__(64) void row_max_kernel(const float* __restrict__ x,
                                                     float* __restrict__ key) {
  int node = blockIdx.x, lane = threadIdx.x;
  float v = fmaxf(x[(size_t)node * 128 + lane], x[(size_t)node * 128 + 64 + lane]);
#pragma unroll
  for (int off = 32; off; off >>= 1) v = fmaxf(v, __shfl_down(v, off));
  if (lane == 0) key[node] = v;
}

__global__ __launch_bounds__(64) void select_topk_kernel(
    const float* __restrict__ key, int* __restrict__ sel) {
  __shared__ float keys[NPG];
  int g = blockIdx.x, t = threadIdx.x;
  keys[t] = key[(size_t)g * NPG + t];
  __syncthreads();
  float myk = keys[t];
  int rank = 0;
  for (int j = 0; j < NPG; ++j) {
    float kj = keys[j];
    rank += (kj > myk) || (kj == myk && j < t);
  }
  if (rank < KK) sel[g * KK + rank] = t;
}

__global__ __launch_bounds__(128) void sort_rows_kernel(
    const float* __restrict__ x, const int* __restrict__ sel,
    float* __restrict__ xp) {
  __shared__ float v[128];
  int b = blockIdx.x;
  int t = threadIdx.x;
  int g = b >> 3, r = b & 7;
  int node = sel[b];
  v[t] = x[(size_t)(g * NPG + node) * 128 + t];
  __syncthreads();
  for (int k = 2; k <= 128; k <<= 1) {
    for (int j = k >> 1; j > 0; j >>= 1) {
      int ixj = t ^ j;
      if (ixj > t) {
        float a = v[t], bb = v[ixj];
        bool asc = ((t & k) == 0);
        if (asc ? (a > bb) : (a < bb)) { v[t] = bb; v[ixj] = a; }
      }
      __syncthreads();
    }
  }
  xp[(size_t)g * (KK * 128) + r * 128 + t] = v[t];
}

// ---------------- fused tail MLP: t1=relu(g3 Wl+bl); t2=relu(t1 Wl1+bl1); out=t2 Wc+bc ----------------
__global__ __launch_bounds__(128) void mlp_tail_kernel(
    const float* __restrict__ g3, const float* __restrict__ Wl,
    const float* __restrict__ bl, const float* __restrict__ Wl1,
    const float* __restrict__ bl1, const float* __restrict__ Wc,
    const float* __restrict__ bc, float* __restrict__ out) {
  __shared__ float buf[128];
  __shared__ float r0[128], r1[128];
  int g = blockIdx.x, t = threadIdx.x;
  buf[t] = g3[(size_t)g * 128 + t];
  __syncthreads();
  float a = 0.f;
  for (int k = 0; k < 128; k++) a += buf[k] * Wl[k * 128 + t];
  float t1 = fmaxf(a + bl[t], 0.f);
  __syncthreads();
  buf[t] = t1;
  __syncthreads();
  a = 0.f;
  for (int k = 0; k < 128; k++) a += buf[k] * Wl1[k * 128 + t];
  float t2 = fmaxf(a + bl1[t], 0.f);
  r0[t] = t2 * Wc[t * 2 + 0];
  r1[t] = t2 * Wc[t * 2 + 1];
  __syncthreads();
  for (int off = 64; off; off >>= 1) {
    if (t < off) { r0[t] += r0[t + off]; r1[t] += r1[t + off]; }
    __syncthreads();
  }
  if (t == 0) {
    out[g * 2 + 0] = r0[0] + bc[0];
    out[g * 2 + 1] = r1[0] + bc[1];
  }
}

// ---------------- launcher ----------------
extern "C" void kernel_launch(void* const* d_in, const int* in_sizes, int n_in,
                              void* d_out, int out_size, void* d_ws, size_t ws_size,
                              hipStream_t stream) {
  const size_t BASE_FLOATS = (size_t)NN * DD * 2 + (size_t)NN * 4;  // X,F,el,er,mx,sm
  const size_t CSR_INTS = (size_t)(NN + 1) + NN + EE + 128;          // row_ptr,cursor,adj,part
  if (ws_size < BASE_FLOATS * sizeof(float)) {
    hipMemsetAsync(d_out, 0, (size_t)out_size * sizeof(float), stream);
    return;
  }
  const bool use_csr = ws_size >= BASE_FLOATS * sizeof(float) + CSR_INTS * sizeof(int);

  const int* h      = (const int*)d_in[0];
  const int* g_src  = (const int*)d_in[1];
  const int* g_dst  = (const int*)d_in[2];
  const int* fg_src = (const int*)d_in[3];
  const int* fg_dst = (const int*)d_in[4];
  const float* temb = (const float*)d_in[5];
  const float* W1 = (const float*)d_in[6];
  const float* al1 = (const float*)d_in[7];
  const float* ar1 = (const float*)d_in[8];
  const float* b1 = (const float*)d_in[9];
  const float* W2 = (const float*)d_in[10];
  const float* al2 = (const float*)d_in[11];
  const float* ar2 = (const float*)d_in[12];
  const float* b2 = (const float*)d_in[13];
  const float* W3 = (const float*)d_in[14];
  const float* al3 = (const float*)d_in[15];
  const float* ar3 = (const float*)d_in[16];
  const float* b3 = (const float*)d_in[17];
  const float* Wf = (const float*)d_in[18];
  const float* bfv = (const float*)d_in[19];
  const float* Wl = (const float*)d_in[20];
  const float* bl = (const float*)d_in[21];
  const float* Wl1 = (const float*)d_in[22];
  const float* bl1 = (const float*)d_in[23];
  const float* Wc = (const float*)d_in[24];
  const float* bc = (const float*)d_in[25];
  float* out = (float*)d_out;

  // ---- workspace layout ----
  float* ws = (float*)d_ws;
  float* X  = ws;
  float* F  = X + (size_t)NN * DD;   // used as bf16 (first half) on CSR path
  float* el = F + (size_t)NN * DD;
  float* er = el + NN;
  float* mx = er + NN;
  float* sm = mx + NN;
  int* row_ptr = (int*)(sm + NN);
  int* cursor  = row_ptr + NN + 1;
  int* adj_src = cursor + NN;
  int* part    = adj_src + EE;
  // rank buffer aliases X (X is first written after CSR build completes):
  int* rankb = (int*)X;              // EE ints = 4 MB << 64 MB X region
  // packed W tables live in mx/sm (unused by CSR-path inner layers):
  bfu* w1h = (bfu*)mx;            // 16384 each
  bfu* w1l = w1h + 16384;
  bfu* w2h = w1l + 16384;
  bfu* w2l = w2h + 16384;
  bfu* wfh = w2l + 16384;
  bfu* wfl = wfh + 16384;          // total 192KB < 512KB (mx region alone)
  // carved from F once F is dead (after layer-2 aggregation):
  float* xp   = F;
  float* f3   = F + 2097152;
  float* g3   = f3 + (size_t)GG * DD;
  float* t1   = g3 + (size_t)GG * DD;
  float* t2   = t1 + (size_t)GG * DD;
  float* keyb = t2 + (size_t)GG * DD;
  int*   sel  = (int*)(keyb + NN);

  const int totalND = NN * DD;

  if (use_csr) {
    bfu* Fb = (bfu*)F;
    // ---- build CSR of inner graph by dst (reused by both GAT layers) ----
    zero_int_kernel<<<NN / 256, 256, 0, stream>>>(cursor, NN);
    hist_rank_kernel<<<EE / 256, 256, 0, stream>>>(g_dst, cursor, rankb, EE);
    scan_block_kernel<<<NN / 1024, 256, 0, stream>>>(cursor, row_ptr, part);
    scan_part_kernel<<<1, 128, 0, stream>>>(part);
    scan_add_kernel<<<(NN + 255) / 256, 256, 0, stream>>>(row_ptr, part, NN, EE);
    scatter2_kernel<<<EE / 256, 256, 0, stream>>>(g_dst, g_src, row_ptr, rankb, adj_src, EE);

    // pack the three 128x128 weights into fragment-ordered split tables
    pack_w_kernel<<<64, 256, 0, stream>>>(W1, w1h, w1l);
    pack_w_kernel<<<64, 256, 0, stream>>>(W2, w2h, w2l);
    pack_w_kernel<<<64, 256, 0, stream>>>(Wf, wfh, wfl);

    // layer 1: F(bf16) = relu(temb[h]) @ W1 (MFMA split) + el/er epilogue
    mfma_gemm<1, 1><<<NN / 64, 256, 0, stream>>>(
        nullptr, temb, h, w1h, w1l, nullptr, Fb, al1, ar1, el, er, nullptr);
    gat_aggregate_csr_kernel<<<NN / 8, 256, 0, stream>>>(Fb, el, er, row_ptr, adj_src, b1, X);

    // layer 2
    mfma_gemm<0, 1><<<NN / 64, 256, 0, stream>>>(
        X, nullptr, nullptr, w2h, w2l, nullptr, Fb, al2, ar2, el, er, nullptr);
    gat_aggregate_csr_kernel<<<NN / 8, 256, 0, stream>>>(Fb, el, er, row_ptr, adj_src, b2, X);

    // linear_forward in-place + fused row-max
    mfma_gemm<0, 2><<<NN / 64, 256, 0, stream>>>(
        X, nullptr, nullptr, wfh, wfl, bfv, X, nullptr, nullptr, nullptr, nullptr, keyb);
  } else {
    embed_relu_kernel<<<totalND / 256, 256, 0, stream>>>(temb, h, X, totalND);
    auto gat_inner = [&](const float* W, const float* al, const float* ar, const float* bb) {
      gemm_kernel<DD, 8><<<NN / 8, 128, 0, stream>>>(X, W, nullptr, F, 0);
      attn_logits_kernel<<<NN, 64, 0, stream>>>(F, al, ar, el, er);
      init_softmax_kernel<<<(NN + 255) / 256, 256, 0, stream>>>(mx, sm, NN);
      fill_f32_kernel<<<totalND / 256, 256, 0, stream>>>(X, 0.f, totalND);
      edge_max_kernel<<<(EE + 255) / 256, 256, 0, stream>>>(el, er, g_src, g_dst, mx, EE);
      edge_expsum_kernel<<<(EE + 255) / 256, 256, 0, stream>>>(el, er, mx, g_src, g_dst, sm, EE);
      edge_aggregate_kernel<<<EE, 128, 0, stream>>>(F, el, er, mx, sm, g_src, g_dst, X, EE);
      bias_relu_kernel<<<totalND / 256, 256, 0, stream>>>(X, bb, totalND);
    };
    gat_inner(W1, al1, ar1, b1);
    gat_inner(W2, al2, ar2, b2);
    gemm_kernel<DD, 8><<<NN / 8, 128, 0, stream>>>(X, Wf, bfv, X, 1);
    row_max_kernel<<<NN, 64, 0, stream>>>(X, keyb);
  }

  // sort pooling -> xp [G, 1024]
  select_topk_kernel<<<GG, 64, 0, stream>>>(keyb, sel);
  sort_rows_kernel<<<GG * KK, 128, 0, stream>>>(X, sel, xp);

  // outer GAT over fg (atomic path — small)
  gemm1024_kernel<<<GG / 8, 256, 0, stream>>>(xp, W3, f3);
  attn_logits_kernel<<<GG, 64, 0, stream>>>(f3, al3, ar3, el, er);
  init_softmax_kernel<<<(GG + 255) / 256, 256, 0, stream>>>(mx, sm, GG);
  fill_f32_kernel<<<(GG * DD + 255) / 256, 256, 0, stream>>>(g3, 0.f, GG * DD);
  edge_max_kernel<<<(EFN + 255) / 256, 256, 0, stream>>>(el, er, fg_src, fg_dst, mx, EFN);
  edge_expsum_kernel<<<(EFN + 255) / 256, 256, 0, stream>>>(el, er, mx, fg_src, fg_dst, sm, EFN);
  edge_aggregate_kernel<<<EFN, 128, 0, stream>>>(f3, el, er, mx, sm, fg_src, fg_dst, g3, EFN);
  bias_relu_kernel<<<(GG * DD + 255) / 256, 256, 0, stream>>>(g3, b3, GG * DD);

  // fused tail: t1 -> t2 -> classifier
  mlp_tail_kernel<<<GG, 128, 0, stream>>>(g3, Wl, bl, Wl1, bl1, Wc, bc, out);
}

// Round 18
// 468.677 us; speedup vs baseline: 1.4594x; 1.0222x over previous
//
#include <hip/hip_runtime.h>
#include <math.h>

#define NN   131072   // total inner nodes
#define GG   2048     // graphs
#define NPG  64       // nodes per graph
#define EE   1048576  // inner edges
#define EFN  32768    // outer edges
#define DD   128      // feature dim
#define KK   8        // sortpool k

typedef unsigned short bfu;  // raw bf16 bits
typedef short bf16x8 __attribute__((ext_vector_type(8)));
typedef float f32x4 __attribute__((ext_vector_type(4)));

static __device__ __forceinline__ bfu f2b(float f) {  // RNE f32 -> bf16
  unsigned u = __float_as_uint(f);
  u += 0x7FFFu + ((u >> 16) & 1u);
  return (bfu)(u >> 16);
}
static __device__ __forceinline__ float b2f(bfu b) {
  return __uint_as_float(((unsigned)b) << 16);
}

// ---------------- utility ----------------
__global__ void fill_f32_kernel(float* __restrict__ p, float v, int nElems) {
  int i = blockIdx.x * 256 + threadIdx.x;
  if (i < nElems) p[i] = v;
}

__global__ void zero_int_kernel(int* __restrict__ p, int nElems) {
  int i = blockIdx.x * 256 + threadIdx.x;
  if (i < nElems) p[i] = 0;
}

__global__ void init_softmax_kernel(float* __restrict__ mx, float* __restrict__ sm, int nElems) {
  int i = blockIdx.x * 256 + threadIdx.x;
  if (i < nElems) { mx[i] = -INFINITY; sm[i] = 0.f; }
}

// x[i] = relu(token_emb[h[node]][d])   (fallback path only)
__global__ void embed_relu_kernel(const float* __restrict__ temb,
                                  const int* __restrict__ h,
                                  float* __restrict__ x, int total) {
  int i = blockIdx.x * 256 + threadIdx.x;
  if (i >= total) return;
  int node = i >> 7, d = i & 127;
  x[i] = fmaxf(temb[h[node] * DD + d], 0.f);
}

// ---------------- small / generic GEMM (outer graph, fallback) ----------------
template <int KD, int ROWS>
__global__ __launch_bounds__(128) void gemm_kernel(
    const float* __restrict__ A, const float* __restrict__ W,
    const float* __restrict__ bias, float* __restrict__ out,
    int relu_flag) {
  __shared__ float As[ROWS * KD];
  const int row0 = blockIdx.x * ROWS;
  const int tid = threadIdx.x;
  for (int i = tid; i < ROWS * KD; i += 128) As[i] = A[(size_t)row0 * KD + i];
  __syncthreads();
  float acc[ROWS];
#pragma unroll
  for (int r = 0; r < ROWS; r++) acc[r] = 0.f;
  for (int k = 0; k < KD; k++) {
    float w = W[k * 128 + tid];
#pragma unroll
    for (int r = 0; r < ROWS; r++) acc[r] += As[r * KD + k] * w;
  }
  float b = bias ? bias[tid] : 0.f;
#pragma unroll
  for (int r = 0; r < ROWS; r++) {
    float v = acc[r] + b;
    if (relu_flag) v = fmaxf(v, 0.f);
    out[(size_t)(row0 + r) * 128 + tid] = v;
  }
}

// ---------------- outer-GAT GEMM: f3[G,128] = xp[G,1024] @ W3[1024,128] ----------------
__global__ __launch_bounds__(256) void gemm1024_kernel(
    const float* __restrict__ A, const float* __restrict__ W,
    float* __restrict__ out) {
  __shared__ float As[8 * 1024];
  __shared__ float red[8][256];
  const int t = threadIdx.x;
  const int row0 = blockIdx.x * 8;
  for (int idx = t; idx < 8 * 256; idx += 256) {
    int r = idx >> 8, c4 = (idx & 255) << 2;
    *(float4*)&As[r * 1024 + c4] = *(const float4*)(A + (size_t)(row0 + r) * 1024 + c4);
  }
  __syncthreads();
  const int col = t & 127, kh = t >> 7;
  const int k0 = kh * 512;
  float acc[8];
#pragma unroll
  for (int r = 0; r < 8; r++) acc[r] = 0.f;
  for (int k = k0; k < k0 + 512; k += 4) {
    float w0 = W[(size_t)(k + 0) * 128 + col];
    float w1 = W[(size_t)(k + 1) * 128 + col];
    float w2 = W[(size_t)(k + 2) * 128 + col];
    float w3 = W[(size_t)(k + 3) * 128 + col];
#pragma unroll
    for (int r = 0; r < 8; r++) {
      float4 a = *(const float4*)&As[r * 1024 + k];
      acc[r] += a.x * w0 + a.y * w1 + a.z * w2 + a.w * w3;
    }
  }
#pragma unroll
  for (int r = 0; r < 8; r++) red[r][t] = acc[r];
  __syncthreads();
  for (int idx = t; idx < 1024; idx += 256) {
    int r = idx >> 7, c = idx & 127;
    out[(size_t)(row0 + r) * 128 + c] = red[r][c] + red[r][128 + c];
  }
}

// ---------------- W pack: fragment-ordered split-bf16 table ----------------
__global__ void pack_w_kernel(const float* __restrict__ W,
                              bfu* __restrict__ hi, bfu* __restrict__ lo) {
  int i = blockIdx.x * 256 + threadIdx.x;  // 0..16383
  if (i >= 16384) return;
  int k = i >> 7, n = i & 127;
  float w = W[i];
  bfu h = f2b(w);
  bfu l = f2b(w - b2f(h));
  int kk = k >> 5, k5 = k & 31, quad = k5 >> 3, j = k5 & 7;
  int tt = n >> 4, m16 = n & 15;
  int pos = ((((kk * 8 + tt) * 4 + quad) * 16) + m16) * 8 + j;
  hi[pos] = h;
  lo[pos] = l;
}

// ---------------- MFMA split-precision GEMM (LDS-free, 32 rows/wave) ----------------
// Two 16-row groups per wave share every B-fragment load (halves L2 B traffic).
template <int SRC_MODE, int EPI>
__global__ __launch_bounds__(256) void mfma_gemm(
    const float* A, const float* __restrict__ temb,
    const int* __restrict__ hidx,
    const bfu* __restrict__ WfHi, const bfu* __restrict__ WfLo,
    const float* __restrict__ bias, void* out,
    const float* __restrict__ al, const float* __restrict__ ar,
    float* __restrict__ el, float* __restrict__ er,
    float* __restrict__ keyb) {
  const int t = threadIdx.x;
  const int lane = t & 63, wv_ = t >> 6;
  const int m16 = lane & 15, quad = lane >> 4;
  const int rowbase = blockIdx.x * 128 + wv_ * 32;
  const float* arow0 = (SRC_MODE == 1) ? (temb + (size_t)hidx[rowbase + m16] * 128)
                                       : (A + (size_t)(rowbase + m16) * 128);
  const float* arow1 = (SRC_MODE == 1) ? (temb + (size_t)hidx[rowbase + 16 + m16] * 128)
                                       : (A + (size_t)(rowbase + 16 + m16) * 128);
  f32x4 acc[2][8];
#pragma unroll
  for (int rg = 0; rg < 2; rg++)
#pragma unroll
    for (int i = 0; i < 8; i++) acc[rg][i] = (f32x4){0.f, 0.f, 0.f, 0.f};
#pragma unroll
  for (int kk = 0; kk < 4; kk++) {
    int k0 = kk * 32 + quad * 8;
    float av0[8], av1[8];
    *(float4*)&av0[0] = *(const float4*)(arow0 + k0);
    *(float4*)&av0[4] = *(const float4*)(arow0 + k0 + 4);
    *(float4*)&av1[0] = *(const float4*)(arow1 + k0);
    *(float4*)&av1[4] = *(const float4*)(arow1 + k0 + 4);
    if (SRC_MODE == 1) {
#pragma unroll
      for (int i = 0; i < 8; i++) {
        av0[i] = fmaxf(av0[i], 0.f);
        av1[i] = fmaxf(av1[i], 0.f);
      }
    }
    bf16x8 ahi0, alo0, ahi1, alo1;
#pragma unroll
    for (int i = 0; i < 8; i++) {
      bfu h0 = f2b(av0[i]);
      alo0[i] = (short)f2b(av0[i] - b2f(h0));
      ahi0[i] = (short)h0;
      bfu h1 = f2b(av1[i]);
      alo1[i] = (short)f2b(av1[i] - b2f(h1));
      ahi1[i] = (short)h1;
    }
#pragma unroll
    for (int tt = 0; tt < 8; tt++) {
      int pos = ((((kk * 8 + tt) * 4 + quad) * 16) + m16) * 8;
      bf16x8 bhi = *(const bf16x8*)&WfHi[pos];
      bf16x8 blo = *(const bf16x8*)&WfLo[pos];
      acc[0][tt] = __builtin_amdgcn_mfma_f32_16x16x32_bf16(ahi0, bhi, acc[0][tt], 0, 0, 0);
      acc[0][tt] = __builtin_amdgcn_mfma_f32_16x16x32_bf16(ahi0, blo, acc[0][tt], 0, 0, 0);
      acc[0][tt] = __builtin_amdgcn_mfma_f32_16x16x32_bf16(alo0, bhi, acc[0][tt], 0, 0, 0);
      acc[1][tt] = __builtin_amdgcn_mfma_f32_16x16x32_bf16(ahi1, bhi, acc[1][tt], 0, 0, 0);
      acc[1][tt] = __builtin_amdgcn_mfma_f32_16x16x32_bf16(ahi1, blo, acc[1][tt], 0, 0, 0);
      acc[1][tt] = __builtin_amdgcn_mfma_f32_16x16x32_bf16(alo1, bhi, acc[1][tt], 0, 0, 0);
    }
  }
#pragma unroll
  for (int rg = 0; rg < 2; rg++) {
    const int rb = rowbase + rg * 16;
    if (EPI == 1) {
      float pl[4] = {0.f, 0.f, 0.f, 0.f}, pr[4] = {0.f, 0.f, 0.f, 0.f};
#pragma unroll
      for (int tt = 0; tt < 8; tt++) {
        int col = tt * 16 + m16;
        float alv = al[col], arv = ar[col];
#pragma unroll
        for (int r = 0; r < 4; r++) {
          float v = acc[rg][tt][r];
          ((bfu*)out)[(size_t)(rb + quad * 4 + r) * 128 + col] = f2b(v);
          pl[r] += v * alv;
          pr[r] += v * arv;
        }
      }
#pragma unroll
      for (int r = 0; r < 4; r++) {
        float a0 = pl[r], a1 = pr[r];
#pragma unroll
        for (int off = 1; off < 16; off <<= 1) {
          a0 += __shfl_xor(a0, off);
          a1 += __shfl_xor(a1, off);
        }
        if (m16 == 0) {
          el[rb + quad * 4 + r] = a0;
          er[rb + quad * 4 + r] = a1;
        }
      }
    } else {  // EPI == 2
      float pm[4] = {-INFINITY, -INFINITY, -INFINITY, -INFINITY};
#pragma unroll
      for (int tt = 0; tt < 8; tt++) {
        int col = tt * 16 + m16;
        float bv = bias[col];
#pragma unroll
        for (int r = 0; r < 4; r++) {
          float v = fmaxf(acc[rg][tt][r] + bv, 0.f);
          ((float*)out)[(size_t)(rb + quad * 4 + r) * 128 + col] = v;
          pm[r] = fmaxf(pm[r], v);
        }
      }
#pragma unroll
      for (int r = 0; r < 4; r++) {
        float a0 = pm[r];
#pragma unroll
        for (int off = 1; off < 16; off <<= 1) a0 = fmaxf(a0, __shfl_xor(a0, off));
        if (m16 == 0) keyb[rb + quad * 4 + r] = a0;
      }
    }
  }
}

// ---------------- attention logits ----------------
__global__ __launch_bounds__(64) void attn_logits_kernel(
    const float* __restrict__ f, const float* __restrict__ al,
    const float* __restrict__ ar, float* __restrict__ el,
    float* __restrict__ er) {
  int node = blockIdx.x, lane = threadIdx.x;
  float v1 = f[(size_t)node * 128 + lane];
  float v2 = f[(size_t)node * 128 + 64 + lane];
  float sl = v1 * al[lane] + v2 * al[64 + lane];
  float sr = v1 * ar[lane] + v2 * ar[64 + lane];
#pragma unroll
  for (int off = 32; off; off >>= 1) {
    sl += __shfl_down(sl, off);
    sr += __shfl_down(sr, off);
  }
  if (lane == 0) { el[node] = sl; er[node] = sr; }
}

// ---------------- CSR build ----------------
__global__ void hist_rank_kernel(const int* __restrict__ dst, int* __restrict__ cnt,
                                 int* __restrict__ rank, int nE) {
  int e = blockIdx.x * 256 + threadIdx.x;
  if (e < nE) rank[e] = atomicAdd(&cnt[dst[e]], 1);
}

__global__ __launch_bounds__(256) void scan_block_kernel(
    const int* __restrict__ cnt, int* __restrict__ excl, int* __restrict__ part) {
  __shared__ int s[256];
  int blk = blockIdx.x, tid = threadIdx.x;
  int base = blk * 1024 + tid * 4;
  int a0 = cnt[base], a1 = cnt[base + 1], a2 = cnt[base + 2], a3 = cnt[base + 3];
  int tsum = a0 + a1 + a2 + a3;
  s[tid] = tsum; __syncthreads();
  for (int off = 1; off < 256; off <<= 1) {
    int v = (tid >= off) ? s[tid - off] : 0;
    __syncthreads();
    s[tid] += v;
    __syncthreads();
  }
  int texcl = s[tid] - tsum;
  excl[base]     = texcl;
  excl[base + 1] = texcl + a0;
  excl[base + 2] = texcl + a0 + a1;
  excl[base + 3] = texcl + a0 + a1 + a2;
  if (tid == 255) part[blk] = s[255];
}

__global__ __launch_bounds__(128) void scan_part_kernel(int* __restrict__ part) {
  __shared__ int s[128];
  int tid = threadIdx.x;
  int orig = part[tid];
  s[tid] = orig; __syncthreads();
  for (int off = 1; off < 128; off <<= 1) {
    int v = (tid >= off) ? s[tid - off] : 0;
    __syncthreads();
    s[tid] += v;
    __syncthreads();
  }
  part[tid] = s[tid] - orig;
}

__global__ void scan_add_kernel(int* __restrict__ row_ptr, const int* __restrict__ part,
                                int n, int total) {
  int i = blockIdx.x * 256 + threadIdx.x;
  if (i < n) row_ptr[i] += part[i >> 10];
  if (i == 0) row_ptr[n] = total;
}

// single-block exclusive scan over 2048 counts (outer graph)
__global__ __launch_bounds__(256) void scan2048_kernel(const int* __restrict__ cnt,
                                                       int* __restrict__ rp, int total) {
  __shared__ int s[256];
  int t = threadIdx.x;
  int base = t * 8;
  int v[8];
  int tsum = 0;
#pragma unroll
  for (int i = 0; i < 8; i++) { v[i] = cnt[base + i]; tsum += v[i]; }
  s[t] = tsum; __syncthreads();
  for (int off = 1; off < 256; off <<= 1) {
    int x = (t >= off) ? s[t - off] : 0;
    __syncthreads();
    s[t] += x;
    __syncthreads();
  }
  int excl = s[t] - tsum;
#pragma unroll
  for (int i = 0; i < 8; i++) { rp[base + i] = excl; excl += v[i]; }
  if (t == 255) rp[2048] = total;
}

__global__ void scatter2_kernel(const int* __restrict__ dst, const int* __restrict__ src,
                                const int* __restrict__ row_ptr, const int* __restrict__ rank,
                                int* __restrict__ adj_src, int nE) {
  int e = blockIdx.x * 256 + threadIdx.x;
  if (e >= nE) return;
  adj_src[row_ptr[dst[e]] + rank[e]] = src[e];
}

// ---------------- fused CSR GAT aggregation: 32-lane group per dst (bf16 F) ----------------
__global__ __launch_bounds__(256) void gat_aggregate_csr_kernel(
    const bfu* __restrict__ F, const float* __restrict__ el,
    const float* __restrict__ er, const int* __restrict__ row_ptr,
    const int* __restrict__ adj_src,
    const float* __restrict__ bias, float* __restrict__ outX) {
  const int t = threadIdx.x;
  const int l = t & 31;
  const int gb = t & 32;
  const int d = blockIdx.x * 8 + (t >> 5);
  const int c0 = l * 4;
  int beg = row_ptr[d];
  int n = row_ptr[d + 1] - beg;
  float4 bv = *(const float4*)&bias[c0];
  if (n == 0) {
    float4 o;
    o.x = fmaxf(bv.x, 0.f); o.y = fmaxf(bv.y, 0.f);
    o.z = fmaxf(bv.z, 0.f); o.w = fmaxf(bv.w, 0.f);
    *(float4*)&outX[(size_t)d * 128 + c0] = o;
    return;
  }
  float er_d = er[d];
  float4 acc = make_float4(0.f, 0.f, 0.f, 0.f);
  if (n <= 32) {
    int sv = 0; float sc = -INFINITY;
    if (l < n) {
      sv = adj_src[beg + l];
      float v = el[sv] + er_d;
      sc = v > 0.f ? v : 0.2f * v;
    }
    float m = sc;
#pragma unroll
    for (int off = 16; off; off >>= 1) m = fmaxf(m, __shfl_xor(m, off));
    float ex = (l < n) ? expf(sc - m) : 0.f;
    float s = ex;
#pragma unroll
    for (int off = 16; off; off >>= 1) s += __shfl_xor(s, off);
    float wt = ex / s;
    for (int j = 0; j < n; j += 4) {
      int   s0 = __shfl(sv, gb + j);
      float w0 = __shfl(wt, gb + j);
      int   j1 = (j + 1 < n) ? j + 1 : j;
      int   s1 = __shfl(sv, gb + j1); float w1 = (j + 1 < n) ? __shfl(wt, gb + j1) : 0.f;
      int   j2 = (j + 2 < n) ? j + 2 : j;
      int   s2 = __shfl(sv, gb + j2); float w2 = (j + 2 < n) ? __shfl(wt, gb + j2) : 0.f;
      int   j3 = (j + 3 < n) ? j + 3 : j;
      int   s3 = __shfl(sv, gb + j3); float w3 = (j + 3 < n) ? __shfl(wt, gb + j3) : 0.f;
      ushort4 f0 = *(const ushort4*)&F[(size_t)s0 * 128 + c0];
      ushort4 f1 = *(const ushort4*)&F[(size_t)s1 * 128 + c0];
      ushort4 f2 = *(const ushort4*)&F[(size_t)s2 * 128 + c0];
      ushort4 f3 = *(const ushort4*)&F[(size_t)s3 * 128 + c0];
      acc.x += w0 * b2f(f0.x) + w1 * b2f(f1.x) + w2 * b2f(f2.x) + w3 * b2f(f3.x);
      acc.y += w0 * b2f(f0.y) + w1 * b2f(f1.y) + w2 * b2f(f2.y) + w3 * b2f(f3.y);
      acc.z += w0 * b2f(f0.z) + w1 * b2f(f1.z) + w2 * b2f(f2.z) + w3 * b2f(f3.z);
      acc.w += w0 * b2f(f0.w) + w1 * b2f(f1.w) + w2 * b2f(f2.w) + w3 * b2f(f3.w);
    }
  } else {
    float lm = -INFINITY;
    for (int e = l; e < n; e += 32) {
      int sv = adj_src[beg + e];
      float v = el[sv] + er_d;
      v = v > 0.f ? v : 0.2f * v;
      lm = fmaxf(lm, v);
    }
#pragma unroll
    for (int off = 16; off; off >>= 1) lm = fmaxf(lm, __shfl_xor(lm, off));
    float ls = 0.f;
    for (int e = l; e < n; e += 32) {
      int sv = adj_src[beg + e];
      float v = el[sv] + er_d;
      v = v > 0.f ? v : 0.2f * v;
      ls += expf(v - lm);
    }
#pragma unroll
    for (int off = 16; off; off >>= 1) ls += __shfl_xor(ls, off);
    for (int base = 0; base < n; base += 32) {
      int e = base + l;
      int sv = 0; float wt = 0.f;
      if (e < n) {
        sv = adj_src[beg + e];
        float v = el[sv] + er_d;
        v = v > 0.f ? v : 0.2f * v;
        wt = expf(v - lm) / ls;
      }
      int cnt = min(32, n - base);
      for (int j = 0; j < cnt; ++j) {
        int s0 = __shfl(sv, gb + j);
        float w0 = __shfl(wt, gb + j);
        ushort4 f0 = *(const ushort4*)&F[(size_t)s0 * 128 + c0];
        acc.x += w0 * b2f(f0.x);
        acc.y += w0 * b2f(f0.y);
        acc.z += w0 * b2f(f0.z);
        acc.w += w0 * b2f(f0.w);
      }
    }
  }
  float4 o;
  o.x = fmaxf(acc.x + bv.x, 0.f);
  o.y = fmaxf(acc.y + bv.y, 0.f);
  o.z = fmaxf(acc.z + bv.z, 0.f);
  o.w = fmaxf(acc.w + bv.w, 0.f);
  *(float4*)&outX[(size_t)d * 128 + c0] = o;
}

// ---------------- fused outer GAT aggregation (fp32 f3 gather) ----------------
__global__ __launch_bounds__(256) void gat_aggregate_outer_kernel(
    const float* __restrict__ F, const float* __restrict__ el,
    const float* __restrict__ er, const int* __restrict__ row_ptr,
    const int* __restrict__ adj_src,
    const float* __restrict__ bias, float* __restrict__ outG) {
  const int t = threadIdx.x;
  const int l = t & 31;
  const int gb = t & 32;
  const int d = blockIdx.x * 8 + (t >> 5);
  const int c0 = l * 4;
  int beg = row_ptr[d];
  int n = row_ptr[d + 1] - beg;
  float4 bv = *(const float4*)&bias[c0];
  if (n == 0) {
    float4 o;
    o.x = fmaxf(bv.x, 0.f); o.y = fmaxf(bv.y, 0.f);
    o.z = fmaxf(bv.z, 0.f); o.w = fmaxf(bv.w, 0.f);
    *(float4*)&outG[(size_t)d * 128 + c0] = o;
    return;
  }
  float er_d = er[d];
  float4 acc = make_float4(0.f, 0.f, 0.f, 0.f);
  if (n <= 32) {
    int sv = 0; float sc = -INFINITY;
    if (l < n) {
      sv = adj_src[beg + l];
      float v = el[sv] + er_d;
      sc = v > 0.f ? v : 0.2f * v;
    }
    float m = sc;
#pragma unroll
    for (int off = 16; off; off >>= 1) m = fmaxf(m, __shfl_xor(m, off));
    float ex = (l < n) ? expf(sc - m) : 0.f;
    float s = ex;
#pragma unroll
    for (int off = 16; off; off >>= 1) s += __shfl_xor(s, off);
    float wt = ex / s;
    for (int j = 0; j < n; ++j) {
      int   s0 = __shfl(sv, gb + j);
      float w0 = __shfl(wt, gb + j);
      float4 f0 = *(const float4*)&F[(size_t)s0 * 128 + c0];
      acc.x += w0 * f0.x; acc.y += w0 * f0.y;
      acc.z += w0 * f0.z; acc.w += w0 * f0.w;
    }
  } else {
    float lm = -INFINITY;
    for (int e = l; e < n; e += 32) {
      int sv = adj_src[beg + e];
      float v = el[sv] + er_d;
      v = v > 0.f ? v : 0.2f * v;
      lm = fmaxf(lm, v);
    }
#pragma unroll
    for (int off = 16; off; off >>= 1) lm = fmaxf(lm, __shfl_xor(lm, off));
    float ls = 0.f;
    for (int e = l; e < n; e += 32) {
      int sv = adj_src[beg + e];
      float v = el[sv] + er_d;
      v = v > 0.f ? v : 0.2f * v;
      ls += expf(v - lm);
    }
#pragma unroll
    for (int off = 16; off; off >>= 1) ls += __shfl_xor(ls, off);
    for (int base = 0; base < n; base += 32) {
      int e = base + l;
      int sv = 0; float wt = 0.f;
      if (e < n) {
        sv = adj_src[beg + e];
        float v = el[sv] + er_d;
        v = v > 0.f ? v : 0.2f * v;
        wt = expf(v - lm) / ls;
      }
      int cnt = min(32, n - base);
      for (int j = 0; j < cnt; ++j) {
        int s0 = __shfl(sv, gb + j);
        float w0 = __shfl(wt, gb + j);
        float4 f0 = *(const float4*)&F[(size_t)s0 * 128 + c0];
        acc.x += w0 * f0.x; acc.y += w0 * f0.y;
        acc.z += w0 * f0.z; acc.w += w0 * f0.w;
      }
    }
  }
  float4 o;
  o.x = fmaxf(acc.x + bv.x, 0.f);
  o.y = fmaxf(acc.y + bv.y, 0.f);
  o.z = fmaxf(acc.z + bv.z, 0.f);
  o.w = fmaxf(acc.w + bv.w, 0.f);
  *(float4*)&outG[(size_t)d * 128 + c0] = o;
}

// ---------------- atomic-path edge kernels (fallback only) ----------------
static __device__ __forceinline__ void atomicMaxF(float* addr, float v) {
  int iv = __float_as_int(v);
  if (iv >= 0) atomicMax((int*)addr, iv);
  else atomicMin((unsigned int*)addr, (unsigned int)iv);
}

static __device__ __forceinline__ float edge_score(const float* el, const float* er,
                                                   int sv, int dv) {
  float v = el[sv] + er[dv];
  return v > 0.f ? v : 0.2f * v;
}

__global__ void edge_max_kernel(const float* __restrict__ el,
                                const float* __restrict__ er,
                                const int* __restrict__ src,
                                const int* __restrict__ dst,
                                float* __restrict__ m, int nE) {
  int e = blockIdx.x * 256 + threadIdx.x;
  if (e >= nE) return;
  atomicMaxF(&m[dst[e]], edge_score(el, er, src[e], dst[e]));
}

__global__ void edge_expsum_kernel(const float* __restrict__ el,
                                   const float* __restrict__ er,
                                   const float* __restrict__ m,
                                   const int* __restrict__ src,
                                   const int* __restrict__ dst,
                                   float* __restrict__ s, int nE) {
  int e = blockIdx.x * 256 + threadIdx.x;
  if (e >= nE) return;
  int d = dst[e];
  atomicAdd(&s[d], expf(edge_score(el, er, src[e], d) - m[d]));
}

__global__ __launch_bounds__(128) void edge_aggregate_kernel(
    const float* __restrict__ f, const float* __restrict__ el,
    const float* __restrict__ er, const float* __restrict__ m,
    const float* __restrict__ s, const int* __restrict__ src,
    const int* __restrict__ dst, float* __restrict__ out, int nE) {
  int e = blockIdx.x;
  int d = threadIdx.x;
  int sv = src[e], dv = dst[e];
  float alpha = expf(edge_score(el, er, sv, dv) - m[dv]) / s[dv];
  atomicAdd(&out[(size_t)dv * 128 + d], alpha * f[(size_t)sv * 128 + d]);
}

__global__ void bias_relu_kernel(float* __restrict__ x,
                                 const float* __restrict__ b, int total) {
  int i = blockIdx.x * 256 + threadIdx.x;
  if (i >= total) return;
  x[i] = fmaxf(x[i] + b[i & 127], 0.f);
}

// ---------------- sort pooling ----------------
__global__ __launch_bounds__(64) void row_max_kernel(const float* __restrict__ x,
                                                     float* __restrict__ key) {
  int node = blockIdx.x, lane = threadIdx.x;
  float v = fmaxf(x[(size_t)node * 128 + lane], x[(size_t)node * 128 + 64 + lane]);
#pragma unroll
  for (int off = 32; off; off >>= 1) v = fmaxf(v, __shfl_down(v, off));
  if (lane == 0) key[node] = v;
}

__global__ __launch_bounds__(64) void select_topk_kernel(
    const float* __restrict__ key, int* __restrict__ sel) {
  __shared__ float keys[NPG];
  int g = blockIdx.x, t = threadIdx.x;
  keys[t] = key[(size_t)g * NPG + t];
  __syncthreads();
  float myk = keys[t];
  int rank = 0;
  for (int j = 0; j < NPG; ++j) {
    float kj = keys[j];
    rank += (kj > myk) || (kj == myk && j < t);
  }
  if (rank < KK) sel[g * KK + rank] = t;
}

__global__ __launch_bounds__(128) void sort_rows_kernel(
    const float* __restrict__ x, const int* __restrict__ sel,
    float* __restrict__ xp) {
  __shared__ float v[128];
  int b = blockIdx.x;
  int t = threadIdx.x;
  int g = b >> 3, r = b & 7;
  int node = sel[b];
  v[t] = x[(size_t)(g * NPG + node) * 128 + t];
  __syncthreads();
  for (int k = 2; k <= 128; k <<= 1) {
    for (int j = k >> 1; j > 0; j >>= 1) {
      int ixj = t ^ j;
      if (ixj > t) {
        float a = v[t], bb = v[ixj];
        bool asc = ((t & k) == 0);
        if (asc ? (a > bb) : (a < bb)) { v[t] = bb; v[ixj] = a; }
      }
      __syncthreads();
    }
  }
  xp[(size_t)g * (KK * 128) + r * 128 + t] = v[t];
}

// ---------------- fused tail MLP ----------------
__global__ __launch_bounds__(128) void mlp_tail_kernel(
    const float* __restrict__ g3, const float* __restrict__ Wl,
    const float* __restrict__ bl, const float* __restrict__ Wl1,
    const float* __restrict__ bl1, const float* __restrict__ Wc,
    const float* __restrict__ bc, float* __restrict__ out) {
  __shared__ float buf[128];
  __shared__ float r0[128], r1[128];
  int g = blockIdx.x, t = threadIdx.x;
  buf[t] = g3[(size_t)g * 128 + t];
  __syncthreads();
  float a = 0.f;
  for (int k = 0; k < 128; k++) a += buf[k] * Wl[k * 128 + t];
  float t1 = fmaxf(a + bl[t], 0.f);
  __syncthreads();
  buf[t] = t1;
  __syncthreads();
  a = 0.f;
  for (int k = 0; k < 128; k++) a += buf[k] * Wl1[k * 128 + t];
  float t2 = fmaxf(a + bl1[t], 0.f);
  r0[t] = t2 * Wc[t * 2 + 0];
  r1[t] = t2 * Wc[t * 2 + 1];
  __syncthreads();
  for (int off = 64; off; off >>= 1) {
    if (t < off) { r0[t] += r0[t + off]; r1[t] += r1[t + off]; }
    __syncthreads();
  }
  if (t == 0) {
    out[g * 2 + 0] = r0[0] + bc[0];
    out[g * 2 + 1] = r1[0] + bc[1];
  }
}

// ---------------- launcher ----------------
extern "C" void kernel_launch(void* const* d_in, const int* in_sizes, int n_in,
                              void* d_out, int out_size, void* d_ws, size_t ws_size,
                              hipStream_t stream) {
  const size_t BASE_FLOATS = (size_t)NN * DD * 2 + (size_t)NN * 4;  // X,F,el,er,mx,sm
  const size_t CSR_INTS = (size_t)(NN + 1) + NN + EE + 128;          // row_ptr,cursor,adj,part
  if (ws_size < BASE_FLOATS * sizeof(float)) {
    hipMemsetAsync(d_out, 0, (size_t)out_size * sizeof(float), stream);
    return;
  }
  const bool use_csr = ws_size >= BASE_FLOATS * sizeof(float) + CSR_INTS * sizeof(int);

  const int* h      = (const int*)d_in[0];
  const int* g_src  = (const int*)d_in[1];
  const int* g_dst  = (const int*)d_in[2];
  const int* fg_src = (const int*)d_in[3];
  const int* fg_dst = (const int*)d_in[4];
  const float* temb = (const float*)d_in[5];
  const float* W1 = (const float*)d_in[6];
  const float* al1 = (const float*)d_in[7];
  const float* ar1 = (const float*)d_in[8];
  const float* b1 = (const float*)d_in[9];
  const float* W2 = (const float*)d_in[10];
  const float* al2 = (const float*)d_in[11];
  const float* ar2 = (const float*)d_in[12];
  const float* b2 = (const float*)d_in[13];
  const float* W3 = (const float*)d_in[14];
  const float* al3 = (const float*)d_in[15];
  const float* ar3 = (const float*)d_in[16];
  const float* b3 = (const float*)d_in[17];
  const float* Wf = (const float*)d_in[18];
  const float* bfv = (const float*)d_in[19];
  const float* Wl = (const float*)d_in[20];
  const float* bl = (const float*)d_in[21];
  const float* Wl1 = (const float*)d_in[22];
  const float* bl1 = (const float*)d_in[23];
  const float* Wc = (const float*)d_in[24];
  const float* bc = (const float*)d_in[25];
  float* out = (float*)d_out;

  // ---- workspace layout ----
  float* ws = (float*)d_ws;
  float* X  = ws;
  float* F  = X + (size_t)NN * DD;   // used as bf16 (first half) on CSR path
  float* el = F + (size_t)NN * DD;
  float* er = el + NN;
  float* mx = er + NN;
  float* sm = mx + NN;
  int* row_ptr = (int*)(sm + NN);
  int* cursor  = row_ptr + NN + 1;
  int* adj_src = cursor + NN;
  int* part    = adj_src + EE;
  // rank buffer aliases X (X first written after CSR build):
  int* rankb = (int*)X;
  // packed W tables live in mx/sm:
  bfu* w1h = (bfu*)mx;
  bfu* w1l = w1h + 16384;
  bfu* w2h = w1l + 16384;
  bfu* w2l = w2h + 16384;
  bfu* wfh = w2l + 16384;
  bfu* wfl = wfh + 16384;
  // outer-graph CSR aliases X region (X dead after sort_rows):
  int* ocnt  = (int*)X;               // 2048
  int* orp   = ocnt + 2048;           // 2049
  int* orank = orp + 2080;            // EFN
  int* oadj  = orank + EFN;           // EFN
  // carved from F once F is dead:
  float* xp   = F;
  float* f3   = F + 2097152;
  float* g3   = f3 + (size_t)GG * DD;
  float* t1   = g3 + (size_t)GG * DD;
  float* t2   = t1 + (size_t)GG * DD;
  float* keyb = t2 + (size_t)GG * DD;
  int*   sel  = (int*)(keyb + NN);

  const int totalND = NN * DD;

  if (use_csr) {
    bfu* Fb = (bfu*)F;
    // ---- inner CSR ----
    zero_int_kernel<<<NN / 256, 256, 0, stream>>>(cursor, NN);
    hist_rank_kernel<<<EE / 256, 256, 0, stream>>>(g_dst, cursor, rankb, EE);
    scan_block_kernel<<<NN / 1024, 256, 0, stream>>>(cursor, row_ptr, part);
    scan_part_kernel<<<1, 128, 0, stream>>>(part);
    scan_add_kernel<<<(NN + 255) / 256, 256, 0, stream>>>(row_ptr, part, NN, EE);
    scatter2_kernel<<<EE / 256, 256, 0, stream>>>(g_dst, g_src, row_ptr, rankb, adj_src, EE);

    pack_w_kernel<<<64, 256, 0, stream>>>(W1, w1h, w1l);
    pack_w_kernel<<<64, 256, 0, stream>>>(W2, w2h, w2l);
    pack_w_kernel<<<64, 256, 0, stream>>>(Wf, wfh, wfl);

    // layer 1
    mfma_gemm<1, 1><<<NN / 128, 256, 0, stream>>>(
        nullptr, temb, h, w1h, w1l, nullptr, Fb, al1, ar1, el, er, nullptr);
    gat_aggregate_csr_kernel<<<NN / 8, 256, 0, stream>>>(Fb, el, er, row_ptr, adj_src, b1, X);

    // layer 2
    mfma_gemm<0, 1><<<NN / 128, 256, 0, stream>>>(
        X, nullptr, nullptr, w2h, w2l, nullptr, Fb, al2, ar2, el, er, nullptr);
    gat_aggregate_csr_kernel<<<NN / 8, 256, 0, stream>>>(Fb, el, er, row_ptr, adj_src, b2, X);

    // linear_forward in-place + fused row-max
    mfma_gemm<0, 2><<<NN / 128, 256, 0, stream>>>(
        X, nullptr, nullptr, wfh, wfl, bfv, X, nullptr, nullptr, nullptr, nullptr, keyb);

    // sort pooling -> xp
    select_topk_kernel<<<GG, 64, 0, stream>>>(keyb, sel);
    sort_rows_kernel<<<GG * KK, 128, 0, stream>>>(X, sel, xp);

    // outer GAT: GEMM + logits + mini-CSR + fused aggregate
    gemm1024_kernel<<<GG / 8, 256, 0, stream>>>(xp, W3, f3);
    attn_logits_kernel<<<GG, 64, 0, stream>>>(f3, al3, ar3, el, er);
    zero_int_kernel<<<GG / 256, 256, 0, stream>>>(ocnt, GG);
    hist_rank_kernel<<<EFN / 256, 256, 0, stream>>>(fg_dst, ocnt, orank, EFN);
    scan2048_kernel<<<1, 256, 0, stream>>>(ocnt, orp, EFN);
    scatter2_kernel<<<EFN / 256, 256, 0, stream>>>(fg_dst, fg_src, orp, orank, oadj, EFN);
    gat_aggregate_outer_kernel<<<GG / 8, 256, 0, stream>>>(f3, el, er, orp, oadj, b3, g3);

    // fused tail
    mlp_tail_kernel<<<GG, 128, 0, stream>>>(g3, Wl, bl, Wl1, bl1, Wc, bc, out);
  } else {
    embed_relu_kernel<<<totalND / 256, 256, 0, stream>>>(temb, h, X, totalND);
    auto gat_inner = [&](const float* W, const float* al, const float* ar, const float* bb) {
      gemm_kernel<DD, 8><<<NN / 8, 128, 0, stream>>>(X, W, nullptr, F, 0);
      attn_logits_kernel<<<NN, 64, 0, stream>>>(F, al, ar, el, er);
      init_softmax_kernel<<<(NN + 255) / 256, 256, 0, stream>>>(mx, sm, NN);
      fill_f32_kernel<<<totalND / 256, 256, 0, stream>>>(X, 0.f, totalND);
      edge_max_kernel<<<(EE + 255) / 256, 256, 0, stream>>>(el, er, g_src, g_dst, mx, EE);
      edge_expsum_kernel<<<(EE + 255) / 256, 256, 0, stream>>>(el, er, mx, g_src, g_dst, sm, EE);
      edge_aggregate_kernel<<<EE, 128, 0, stream>>>(F, el, er, mx, sm, g_src, g_dst, X, EE);
      bias_relu_kernel<<<totalND / 256, 256, 0, stream>>>(X, bb, totalND);
    };
    gat_inner(W1, al1, ar1, b1);
    gat_inner(W2, al2, ar2, b2);
    gemm_kernel<DD, 8><<<NN / 8, 128, 0, stream>>>(X, Wf, bfv, X, 1);
    row_max_kernel<<<NN, 64, 0, stream>>>(X, keyb);

    select_topk_kernel<<<GG, 64, 0, stream>>>(keyb, sel);
    sort_rows_kernel<<<GG * KK, 128, 0, stream>>>(X, sel, xp);

    gemm1024_kernel<<<GG / 8, 256, 0, stream>>>(xp, W3, f3);
    attn_logits_kernel<<<GG, 64, 0, stream>>>(f3, al3, ar3, el, er);
    init_softmax_kernel<<<(GG + 255) / 256, 256, 0, stream>>>(mx, sm, GG);
    fill_f32_kernel<<<(GG * DD + 255) / 256, 256, 0, stream>>>(g3, 0.f, GG * DD);
    edge_max_kernel<<<(EFN + 255) / 256, 256, 0, stream>>>(el, er, fg_src, fg_dst, mx, EFN);
    edge_expsum_kernel<<<(EFN + 255) / 256, 256, 0, stream>>>(el, er, mx, fg_src, fg_dst, sm, EFN);
    edge_aggregate_kernel<<<EFN, 128, 0, stream>>>(f3, el, er, mx, sm, fg_src, fg_dst, g3, EFN);
    bias_relu_kernel<<<(GG * DD + 255) / 256, 256, 0, stream>>>(g3, b3, GG * DD);
    mlp_tail_kernel<<<GG, 128, 0, stream>>>(g3, Wl, bl, Wl1, bl1, Wc, bc, out);
  }
}